// Round 15
// baseline (251.571 us; speedup 1.0000x reference)
//
#include <hip/hip_runtime.h>
#include <hip/hip_bf16.h>
#include <math.h>

#define B_SZ 8192
#define I_SZ 1024
#define O_SZ 1024
#define NCP  6

typedef __attribute__((ext_vector_type(8))) short bf16x8;
typedef __attribute__((ext_vector_type(4))) float f32x4;

__device__ __forceinline__ unsigned short f2bf(float f) {
  union { float f; unsigned int u; } v; v.f = f;
  unsigned int u = v.u;
  u += 0x7FFFu + ((u >> 16) & 1u);   // round-to-nearest-even
  return (unsigned short)(u >> 16);
}

__global__ void cvt_f32_to_bf16(const float* __restrict__ src,
                                unsigned short* __restrict__ dst, int n4) {
  int idx = blockIdx.x * blockDim.x + threadIdx.x;
  int stride = gridDim.x * blockDim.x;
  for (int i = idx; i < n4; i += stride) {
    float4 v = reinterpret_cast<const float4*>(src)[i];
    ushort4 o;
    o.x = f2bf(v.x); o.y = f2bf(v.y); o.z = f2bf(v.z); o.w = f2bf(v.w);
    reinterpret_cast<ushort4*>(dst)[i] = o;
  }
}

__device__ __forceinline__ void gload_lds16(const void* g, void* l) {
  __builtin_amdgcn_global_load_lds(
      (const __attribute__((address_space(1))) void*)g,
      (__attribute__((address_space(3))) void*)l, 16, 0, 0);
}

#define BM 256
#define BN 128
#define BK 64
#define NT 96    // 6 j-chunks x 16 K-tiles

// out[b,o] = sum_j c[b,j] * ( sum_i W[j,o,i]*x[b,i] + bias[j,o] )
// R12's verified skeleton (part[] AGPR chain + per-j fold, A via LDS-DMA
// ring-3 with both-sides XOR swizzle, 1 counted-vmcnt + 1 barrier per tile)
// with B MOVED OUT OF LDS: B fragments are register-prefetched one tile
// ahead directly from L2 (W panel/block = 1.5MB, L2-resident; per-lane
// gather = R11's verified addressing, but issue-early/consume-late per T14
// so the L2 latency hides under a full tile of compute). LDS pipe load
// drops from ~176KB/tile/CU to ~96KB (A reads 64KB + A DMA-writes 32KB).
// vmcnt ledger (uniform): per tile issue {4 A-DMA(t+2), 8 B-loads(t+1)}=12;
// mid-tile vmcnt(12) retires tile t-1's 12 (B(t) regs + A(t+1) DMA);
// end-of-tile s_barrier publishes A(t+1) block-wide. Tail: 94 -> vmcnt(8),
// 95 -> vmcnt(0). 6-tile unroll keeps slots/parity compile-time (rule #20).
__global__ __launch_bounds__(512, 1) void pfl_gemm(
    const unsigned short* __restrict__ xb,
    const unsigned short* __restrict__ wb,
    const float* __restrict__ phase,
    const float* __restrict__ bias,
    float* __restrict__ out) {
  __shared__ __align__(16) unsigned short Abuf[3][BM * BK];  // 3x32 KB
  __shared__ __align__(16) float c4[NCP][BM];                // 6 KB

  const int nbn = O_SZ / BN;  // 8
  int bid = (int)blockIdx.x;  // 256 blocks (divisible by 8)
  int swz = (bid & 7) * 32 + (bid >> 3);  // bijective XCD remap
  int brow = (swz / nbn) * BM;
  int bcol = (swz % nbn) * BN;

  int tid = (int)threadIdx.x;
  int lane = tid & 63;
  int wid = tid >> 6;        // 0..7
  int wr = wid >> 1;         // 0..3 (M)
  int wc = wid & 1;          // 0..1 (N)

  // ---- Catmull-Rom coefficients, layout [j][row] for vectorized folds ----
  if (tid < BM) {
    float ph = phase[brow + tid];
    const float two_pi = 6.2831855f;
    float pm = fmodf(ph, two_pi);              // ph >= 0 -> trunc == floor mod
    float pos = pm * (float)(6.0 / 6.283185307179586);
    float base = floorf(pos);
    int bi = (int)base;
    float t = pos - base;
    float t2 = t * t, t3 = t2 * t;
    float w0 = -0.5f * t + t2 - 0.5f * t3;
    float w1 = 1.0f - 2.5f * t2 + 1.5f * t3;
    float w2 = 0.5f * t + 2.0f * t2 - 1.5f * t3;
    float w3 = -0.5f * t2 + 0.5f * t3;
    float cc[NCP] = {0.f, 0.f, 0.f, 0.f, 0.f, 0.f};
    cc[((bi - 1) % NCP + NCP) % NCP] += w0;
    cc[(bi % NCP + NCP) % NCP]       += w1;
    cc[((bi + 1) % NCP + NCP) % NCP] += w2;
    cc[((bi + 2) % NCP + NCP) % NCP] += w3;
    for (int j = 0; j < NCP; ++j) c4[j][tid] = cc[j];
  }

  f32x4 acc[4][4];   // folded result (VALU-touched once per 16 tiles)
  f32x4 part[4][4];  // pure MFMA chain within a j-chunk (AGPR-resident)
#pragma unroll
  for (int m = 0; m < 4; ++m)
#pragma unroll
    for (int n = 0; n < 4; ++n) {
      acc[m][n] = (f32x4){0.f, 0.f, 0.f, 0.f};
      part[m][n] = (f32x4){0.f, 0.f, 0.f, 0.f};
    }

  // A staging: lane l -> LDS row (8-group + l>>3), linear 16B slot (l&7);
  // global source column pre-swizzled (slot xor row&7), rule #21.
  int swzcol = ((lane & 7) ^ (lane >> 3)) * 8;
  const unsigned short* xsrc =
      xb + (size_t)(brow + wid * 8 + (lane >> 3)) * I_SZ + swzcol;
  // A read-side swizzled base (same as rounds 4-13, conflicts measured 0)
  int lbase = (lane & 15) * 128 + (((lane >> 4) ^ (lane & 7)) & 7) * 16;

  // B per-lane register-gather base: o = bcol + wc*64 + n*16 + (lane&15),
  // k = j*? + ks*64 + kk*32 + (lane>>4)*8  (matches MFMA B-operand layout;
  // same addressing class R11 verified functionally for A)
  const unsigned short* wB =
      wb + (size_t)(bcol + wc * 64 + (lane & 15)) * I_SZ + (lane >> 4) * 8;

#define STAGE_A(T, SLOT) do {                                              \
    const unsigned short* xs_ = xsrc + ((T) & 15) * 64;                    \
    unsigned short* Ad_ = &Abuf[SLOT][(wid * 8) * BK];                     \
    _Pragma("unroll")                                                      \
    for (int p = 0; p < 4; ++p)                                            \
      gload_lds16(xs_ + (size_t)p * 64 * I_SZ, Ad_ + p * 64 * BK);         \
  } while (0)

#define BPRE(T, DST) do {                                                  \
    const unsigned short* p_ =                                             \
        wB + (size_t)((T) >> 4) * O_SZ * I_SZ + ((T) & 15) * 64;           \
    _Pragma("unroll")                                                      \
    for (int n = 0; n < 4; ++n)                                            \
      _Pragma("unroll")                                                    \
      for (int kk = 0; kk < 2; ++kk)                                       \
        DST[n][kk] = *reinterpret_cast<const bf16x8*>(                     \
            p_ + (size_t)n * 16 * I_SZ + kk * 32);                         \
  } while (0)

#define TILE(T, SU, SS, BU, BP, DO_A, DO_B, WAITSTR) do {                  \
    if (DO_A) STAGE_A((T) + 2, SS);                                        \
    if (DO_B) BPRE((T) + 1, BP);                                           \
    const char* Ab_ = (const char*)&Abuf[SU][0];                           \
    bf16x8 af0_[4], af1_[4];                                               \
    _Pragma("unroll")                                                      \
    for (int m = 0; m < 4; ++m)                                            \
      af0_[m] = *reinterpret_cast<const bf16x8*>(                          \
          Ab_ + (wr * 64 + m * 16) * 128 + lbase);                         \
    asm volatile(WAITSTR ::: "memory");                                    \
    __builtin_amdgcn_sched_barrier(0);                                     \
    asm volatile("s_waitcnt lgkmcnt(0)" ::: "memory");                     \
    __builtin_amdgcn_sched_barrier(0);                                     \
    _Pragma("unroll")                                                      \
    for (int m = 0; m < 4; ++m)                                            \
      af1_[m] = *reinterpret_cast<const bf16x8*>(                          \
          Ab_ + (wr * 64 + m * 16) * 128 + (lbase ^ 64));                  \
    __builtin_amdgcn_sched_barrier(0);                                     \
    __builtin_amdgcn_s_setprio(1);                                         \
    _Pragma("unroll")                                                      \
    for (int m = 0; m < 4; ++m)                                            \
      _Pragma("unroll")                                                    \
      for (int n = 0; n < 4; ++n)                                          \
        part[m][n] = __builtin_amdgcn_mfma_f32_16x16x32_bf16(              \
            af0_[m], BU[n][0], part[m][n], 0, 0, 0);                       \
    __builtin_amdgcn_s_setprio(0);                                         \
    asm volatile("s_waitcnt lgkmcnt(0)" ::: "memory");                     \
    __builtin_amdgcn_sched_barrier(0);                                     \
    __builtin_amdgcn_s_setprio(1);                                         \
    _Pragma("unroll")                                                      \
    for (int m = 0; m < 4; ++m)                                            \
      _Pragma("unroll")                                                    \
      for (int n = 0; n < 4; ++n)                                          \
        part[m][n] = __builtin_amdgcn_mfma_f32_16x16x32_bf16(              \
            af1_[m], BU[n][1], part[m][n], 0, 0, 0);                       \
    __builtin_amdgcn_s_setprio(0);                                         \
    if (((T) & 15) == 15) {                                                \
      int j_ = (T) >> 4;                                                   \
      _Pragma("unroll")                                                    \
      for (int m = 0; m < 4; ++m) {                                        \
        f32x4 cv_ = *reinterpret_cast<const f32x4*>(                       \
            &c4[j_][wr * 64 + m * 16 + (lane >> 4) * 4]);                  \
        _Pragma("unroll")                                                  \
        for (int n = 0; n < 4; ++n) {                                      \
          acc[m][n] += cv_ * part[m][n];                                   \
          part[m][n] = (f32x4){0.f, 0.f, 0.f, 0.f};                        \
        }                                                                  \
      }                                                                    \
    }                                                                      \
    __builtin_amdgcn_s_barrier();                                          \
  } while (0)

  bf16x8 bfP[4][2], bfQ[4][2];

  // prologue: A(0),A(1) DMA in flight; B(0) -> bfP; c4 published.
  // __syncthreads drains vmcnt(0): A0/A1/B0 all resident; ledger starts at 0.
  STAGE_A(0, 0);
  STAGE_A(1, 1);
  BPRE(0, bfP);
  __syncthreads();

  for (int u = 0; u < 15; ++u) {
    int t = u * 6;
    TILE(t + 0, 0, 2, bfP, bfQ, 1, 1, "s_waitcnt vmcnt(12)");
    TILE(t + 1, 1, 0, bfQ, bfP, 1, 1, "s_waitcnt vmcnt(12)");
    TILE(t + 2, 2, 1, bfP, bfQ, 1, 1, "s_waitcnt vmcnt(12)");
    TILE(t + 3, 0, 2, bfQ, bfP, 1, 1, "s_waitcnt vmcnt(12)");
    TILE(t + 4, 1, 0, bfP, bfQ, 1, 1, "s_waitcnt vmcnt(12)");
    TILE(t + 5, 2, 1, bfQ, bfP, 1, 1, "s_waitcnt vmcnt(12)");
  }
  // tail: tiles 90..95 (A(96+)/B(96) don't exist; counted waits shrink)
  TILE(90, 0, 2, bfP, bfQ, 1, 1, "s_waitcnt vmcnt(12)");
  TILE(91, 1, 0, bfQ, bfP, 1, 1, "s_waitcnt vmcnt(12)");
  TILE(92, 2, 1, bfP, bfQ, 1, 1, "s_waitcnt vmcnt(12)");
  TILE(93, 0, 2, bfQ, bfP, 1, 1, "s_waitcnt vmcnt(12)");
  TILE(94, 1, 0, bfP, bfQ, 0, 1, "s_waitcnt vmcnt(8)");
  TILE(95, 2, 1, bfQ, bfP, 0, 0, "s_waitcnt vmcnt(0)");

#undef TILE
#undef BPRE
#undef STAGE_A

  // ---- epilogue: bias mix + store (f32) ----
#pragma unroll
  for (int n = 0; n < 4; ++n) {
    int col = bcol + wc * 64 + n * 16 + (lane & 15);
    float b6[NCP];
#pragma unroll
    for (int j = 0; j < NCP; ++j) b6[j] = bias[j * O_SZ + col];
#pragma unroll
    for (int m = 0; m < 4; ++m) {
#pragma unroll
      for (int r = 0; r < 4; ++r) {
        int rloc = wr * 64 + m * 16 + (lane >> 4) * 4 + r;
        float s = 0.f;
#pragma unroll
        for (int j = 0; j < NCP; ++j) s += c4[j][rloc] * b6[j];
        out[(size_t)(brow + rloc) * O_SZ + col] = acc[m][n][r] + s;
      }
    }
  }
}

extern "C" void kernel_launch(void* const* d_in, const int* in_sizes, int n_in,
                              void* d_out, int out_size, void* d_ws, size_t ws_size,
                              hipStream_t stream) {
  (void)in_sizes; (void)n_in; (void)out_size; (void)ws_size;
  const float* x     = (const float*)d_in[0];  // [B, I]
  const float* phase = (const float*)d_in[1];  // [B]
  const float* w     = (const float*)d_in[2];  // [C, O, I]
  const float* bias  = (const float*)d_in[3];  // [C, O]
  float* out = (float*)d_out;                  // [B, O] f32

  unsigned short* xb = (unsigned short*)d_ws;                       // 16 MB
  unsigned short* wb = (unsigned short*)((char*)d_ws +
                        (size_t)B_SZ * I_SZ * sizeof(unsigned short));  // 12 MB

  cvt_f32_to_bf16<<<2048, 256, 0, stream>>>(x, xb, B_SZ * I_SZ / 4);
  cvt_f32_to_bf16<<<1536, 256, 0, stream>>>(w, wb, NCP * O_SZ * I_SZ / 4);

  dim3 grid((B_SZ / BM) * (O_SZ / BN));  // 32*8 = 256
  pfl_gemm<<<grid, 512, 0, stream>>>(xb, wb, phase, bias, out);
}

// Round 16
// 219.043 us; speedup vs baseline: 1.1485x; 1.1485x over previous
//
#include <hip/hip_runtime.h>
#include <hip/hip_bf16.h>
#include <math.h>

#define B_SZ 8192
#define I_SZ 1024
#define O_SZ 1024
#define NCP  6

typedef __attribute__((ext_vector_type(8))) short bf16x8;
typedef __attribute__((ext_vector_type(4))) float f32x4;

__device__ __forceinline__ unsigned short f2bf(float f) {
  union { float f; unsigned int u; } v; v.f = f;
  unsigned int u = v.u;
  u += 0x7FFFu + ((u >> 16) & 1u);   // round-to-nearest-even
  return (unsigned short)(u >> 16);
}

__global__ void cvt_f32_to_bf16(const float* __restrict__ src,
                                unsigned short* __restrict__ dst, int n4) {
  int idx = blockIdx.x * blockDim.x + threadIdx.x;
  int stride = gridDim.x * blockDim.x;
  for (int i = idx; i < n4; i += stride) {
    float4 v = reinterpret_cast<const float4*>(src)[i];
    ushort4 o;
    o.x = f2bf(v.x); o.y = f2bf(v.y); o.z = f2bf(v.z); o.w = f2bf(v.w);
    reinterpret_cast<ushort4*>(dst)[i] = o;
  }
}

__device__ __forceinline__ void gload_lds16(const void* g, void* l) {
  __builtin_amdgcn_global_load_lds(
      (const __attribute__((address_space(1))) void*)g,
      (__attribute__((address_space(3))) void*)l, 16, 0, 0);
}

#define BM 128
#define BN 256
#define BK 64
#define NT 96    // 6 j-chunks x 16 K-tiles
#define NBUF 3

// out[b,o] = sum_j c[b,j] * ( sum_i W[j,o,i]*x[b,i] + bias[j,o] )
// R12's verified body (reg-dbuf fragments, 1 counted-vmcnt + 1 barrier per
// tile, ring-3 LDS-DMA staging w/ both-sides XOR swizzle, part[] AGPR chain
// folded per j-chunk) at a FATTER wave tile: 4 waves (2Mx2N) over a 128x256
// block, wave tile 64x128. This halves LDS-read duplication (R12: every
// A-frag read by 2 waves, B-frag by 4 -> 128KB reads / 48KB unique per
// tile-FLOP; here 96KB) -- attacks the measured binding pipe directly.
// Cost: 4 waves/CU = 1 wave/SIMD (acc+part = 256 AGPR; fits 512 unified
// budget at 1/SIMD). Grid stays 64x4=256 = 1 block/CU, no K-split needed.
// R15's lesson applied: NO per-lane global gathers -- all staging is
// coalesced gload_lds DMA.
// vmcnt ledger: 12 DMA/stage (4 A + 8 B); stage t+2 each tile; end-of-tile
// vmcnt(12) retires t+1's 12 (resident), t+2's 12 stay in flight; tail 0.
__global__ __launch_bounds__(256, 1) void pfl_gemm(
    const unsigned short* __restrict__ xb,
    const unsigned short* __restrict__ wb,
    const float* __restrict__ phase,
    const float* __restrict__ bias,
    float* __restrict__ out) {
  __shared__ __align__(16) unsigned short Abuf[NBUF][BM * BK];  // 3x16 KB
  __shared__ __align__(16) unsigned short Bbuf[NBUF][BN * BK];  // 3x32 KB
  __shared__ __align__(16) float c4[NCP][BM];                   // 3 KB

  const int nbn = O_SZ / BN;  // 4
  int bid = (int)blockIdx.x;  // 256 blocks (divisible by 8)
  int swz = (bid & 7) * 32 + (bid >> 3);  // bijective XCD remap
  int brow = (swz / nbn) * BM;
  int bcol = (swz % nbn) * BN;

  int tid = (int)threadIdx.x;
  int lane = tid & 63;
  int wid = tid >> 6;        // 0..3
  int wr = wid >> 1;         // 0..1 (M): 64-row half
  int wc = wid & 1;          // 0..1 (N): 128-col half

  // ---- Catmull-Rom coefficients, layout [j][row] for vectorized folds ----
  if (tid < BM) {
    float ph = phase[brow + tid];
    const float two_pi = 6.2831855f;
    float pm = fmodf(ph, two_pi);              // ph >= 0 -> trunc == floor mod
    float pos = pm * (float)(6.0 / 6.283185307179586);
    float base = floorf(pos);
    int bi = (int)base;
    float t = pos - base;
    float t2 = t * t, t3 = t2 * t;
    float w0 = -0.5f * t + t2 - 0.5f * t3;
    float w1 = 1.0f - 2.5f * t2 + 1.5f * t3;
    float w2 = 0.5f * t + 2.0f * t2 - 1.5f * t3;
    float w3 = -0.5f * t2 + 0.5f * t3;
    float cc[NCP] = {0.f, 0.f, 0.f, 0.f, 0.f, 0.f};
    cc[((bi - 1) % NCP + NCP) % NCP] += w0;
    cc[(bi % NCP + NCP) % NCP]       += w1;
    cc[((bi + 1) % NCP + NCP) % NCP] += w2;
    cc[((bi + 2) % NCP + NCP) % NCP] += w3;
    for (int j = 0; j < NCP; ++j) c4[j][tid] = cc[j];
  }

  f32x4 acc[4][8];   // folded result: 64 rows x 128 cols per wave
  f32x4 part[4][8];  // pure MFMA chain within a j-chunk (AGPR-resident)
#pragma unroll
  for (int m = 0; m < 4; ++m)
#pragma unroll
    for (int n = 0; n < 8; ++n) {
      acc[m][n] = (f32x4){0.f, 0.f, 0.f, 0.f};
      part[m][n] = (f32x4){0.f, 0.f, 0.f, 0.f};
    }

  // staging: lane l -> LDS row (8-group + l>>3), linear 16B slot (l&7);
  // global source column pre-swizzled (slot xor row&7), rule #21.
  int swzcol = ((lane & 7) ^ (lane >> 3)) * 8;
  const unsigned short* xsrc =
      xb + (size_t)(brow + wid * 8 + (lane >> 3)) * I_SZ + swzcol;
  const unsigned short* wsrc =
      wb + (size_t)(bcol + wid * 8 + (lane >> 3)) * I_SZ + swzcol;

  // read-side swizzled base: slot = chunk ^ (row&7); row&7 == lane&7 here
  int lbase = (lane & 15) * 128 + (((lane >> 4) ^ (lane & 7)) & 7) * 16;

  auto STAGE = [&](int t, int b) {   // 12 DMAs/wave: 4 A + 8 B (32-row stride)
    int ks = (t & 15) * 64;
    int j = t >> 4;
    const unsigned short* xs = xsrc + ks;
    const unsigned short* ws = wsrc + (size_t)j * O_SZ * I_SZ + ks;
    unsigned short* Ad = &Abuf[b][(wid * 8) * BK];
    unsigned short* Bd = &Bbuf[b][(wid * 8) * BK];
#pragma unroll
    for (int p = 0; p < 4; ++p)
      gload_lds16(xs + (size_t)p * 32 * I_SZ, Ad + p * 32 * BK);
#pragma unroll
    for (int p = 0; p < 8; ++p)
      gload_lds16(ws + (size_t)p * 32 * I_SZ, Bd + p * 32 * BK);
  };

  // prologue: tiles 0,1 in flight (24 DMAs); tile 0 resident; c4 published
  STAGE(0, 0);
  STAGE(1, 1);
  asm volatile("s_waitcnt vmcnt(12)" ::: "memory");
  __builtin_amdgcn_sched_barrier(0);
  __syncthreads();

  int cur = 0;
  for (int t = 0; t < NT; ++t) {
    const char* Ab = (const char*)&Abuf[cur][0];
    const char* Bb = (const char*)&Bbuf[cur][0];
    int st = cur + 2; if (st >= NBUF) st -= NBUF;

    // ---- kk=0 fragment reads ----
    bf16x8 af0[4], bf0[8], af1[4], bf1[8];
#pragma unroll
    for (int m = 0; m < 4; ++m)
      af0[m] = *reinterpret_cast<const bf16x8*>(
          Ab + (wr * 64 + m * 16) * 128 + lbase);
#pragma unroll
    for (int n = 0; n < 8; ++n)
      bf0[n] = *reinterpret_cast<const bf16x8*>(
          Bb + (wc * 128 + n * 16) * 128 + lbase);
    // ---- stage t+2 (vmcnt ops; do not disturb lgkm) ----
    if (t + 2 < NT) STAGE(t + 2, st);
    asm volatile("s_waitcnt lgkmcnt(0)" ::: "memory");
    __builtin_amdgcn_sched_barrier(0);

    // ---- issue kk=1 reads: they fly under MFMA0 ----
#pragma unroll
    for (int m = 0; m < 4; ++m)
      af1[m] = *reinterpret_cast<const bf16x8*>(
          Ab + (wr * 64 + m * 16) * 128 + (lbase ^ 64));
#pragma unroll
    for (int n = 0; n < 8; ++n)
      bf1[n] = *reinterpret_cast<const bf16x8*>(
          Bb + (wc * 128 + n * 16) * 128 + (lbase ^ 64));
    __builtin_amdgcn_sched_barrier(0);  // pin kk1 issue before MFMA0

    __builtin_amdgcn_s_setprio(1);
#pragma unroll
    for (int m = 0; m < 4; ++m)
#pragma unroll
      for (int n = 0; n < 8; ++n)
        part[m][n] = __builtin_amdgcn_mfma_f32_16x16x32_bf16(
            af0[m], bf0[n], part[m][n], 0, 0, 0);
    __builtin_amdgcn_s_setprio(0);

    asm volatile("s_waitcnt lgkmcnt(0)" ::: "memory");  // kk1 frags landed
    __builtin_amdgcn_sched_barrier(0);

    __builtin_amdgcn_s_setprio(1);
#pragma unroll
    for (int m = 0; m < 4; ++m)
#pragma unroll
      for (int n = 0; n < 8; ++n)
        part[m][n] = __builtin_amdgcn_mfma_f32_16x16x32_bf16(
            af1[m], bf1[n], part[m][n], 0, 0, 0);
    __builtin_amdgcn_s_setprio(0);

    if ((t & 15) == 15) {  // j-chunk boundary: acc += c[row,j] * part
      int j = t >> 4;
#pragma unroll
      for (int m = 0; m < 4; ++m) {
        f32x4 cv = *reinterpret_cast<const f32x4*>(
            &c4[j][wr * 64 + m * 16 + (lane >> 4) * 4]);
#pragma unroll
        for (int n = 0; n < 8; ++n) {
          acc[m][n] += cv * part[m][n];
          part[m][n] = (f32x4){0.f, 0.f, 0.f, 0.f};
        }
      }
    }

    // ---- tile boundary: counted vmcnt + SINGLE barrier ----
    if (t + 2 < NT)
      asm volatile("s_waitcnt vmcnt(12)" ::: "memory");  // t+1 resident
    else
      asm volatile("s_waitcnt vmcnt(0)" ::: "memory");
    __builtin_amdgcn_sched_barrier(0);
    __builtin_amdgcn_s_barrier();
    ++cur; if (cur == NBUF) cur = 0;
  }

  // ---- epilogue: bias mix + store (f32) ----
#pragma unroll
  for (int n = 0; n < 8; ++n) {
    int col = bcol + wc * 128 + n * 16 + (lane & 15);
    float b6[NCP];
#pragma unroll
    for (int j = 0; j < NCP; ++j) b6[j] = bias[j * O_SZ + col];
#pragma unroll
    for (int m = 0; m < 4; ++m) {
#pragma unroll
      for (int r = 0; r < 4; ++r) {
        int rloc = wr * 64 + m * 16 + (lane >> 4) * 4 + r;
        float s = 0.f;
#pragma unroll
        for (int j = 0; j < NCP; ++j) s += c4[j][rloc] * b6[j];
        out[(size_t)(brow + rloc) * O_SZ + col] = acc[m][n][r] + s;
      }
    }
  }
}

extern "C" void kernel_launch(void* const* d_in, const int* in_sizes, int n_in,
                              void* d_out, int out_size, void* d_ws, size_t ws_size,
                              hipStream_t stream) {
  (void)in_sizes; (void)n_in; (void)out_size; (void)ws_size;
  const float* x     = (const float*)d_in[0];  // [B, I]
  const float* phase = (const float*)d_in[1];  // [B]
  const float* w     = (const float*)d_in[2];  // [C, O, I]
  const float* bias  = (const float*)d_in[3];  // [C, O]
  float* out = (float*)d_out;                  // [B, O] f32

  unsigned short* xb = (unsigned short*)d_ws;                       // 16 MB
  unsigned short* wb = (unsigned short*)((char*)d_ws +
                        (size_t)B_SZ * I_SZ * sizeof(unsigned short));  // 12 MB

  cvt_f32_to_bf16<<<2048, 256, 0, stream>>>(x, xb, B_SZ * I_SZ / 4);
  cvt_f32_to_bf16<<<1536, 256, 0, stream>>>(w, wb, NCP * O_SZ * I_SZ / 4);

  dim3 grid((B_SZ / BM) * (O_SZ / BN));  // 64*4 = 256
  pfl_gemm<<<grid, 256, 0, stream>>>(xb, wb, phase, bias, out);
}

// Round 17
// 136.120 us; speedup vs baseline: 1.8482x; 1.6092x over previous
//
#include <hip/hip_runtime.h>
#include <hip/hip_bf16.h>
#include <math.h>

#define B_SZ 8192
#define I_SZ 1024
#define O_SZ 1024
#define NCP  6

typedef __attribute__((ext_vector_type(8))) short bf16x8;
typedef __attribute__((ext_vector_type(4))) float f32x4;

__device__ __forceinline__ unsigned short f2bf(float f) {
  union { float f; unsigned int u; } v; v.f = f;
  unsigned int u = v.u;
  u += 0x7FFFu + ((u >> 16) & 1u);   // round-to-nearest-even
  return (unsigned short)(u >> 16);
}

__global__ void cvt_f32_to_bf16(const float* __restrict__ src,
                                unsigned short* __restrict__ dst, int n4) {
  int idx = blockIdx.x * blockDim.x + threadIdx.x;
  int stride = gridDim.x * blockDim.x;
  for (int i = idx; i < n4; i += stride) {
    float4 v = reinterpret_cast<const float4*>(src)[i];
    ushort4 o;
    o.x = f2bf(v.x); o.y = f2bf(v.y); o.z = f2bf(v.z); o.w = f2bf(v.w);
    reinterpret_cast<ushort4*>(dst)[i] = o;
  }
}

__device__ __forceinline__ int seg_of(float ph) {
  const float two_pi = 6.2831855f;
  const float scale = (float)(6.0 / 6.283185307179586);
  float pm = fmodf(ph, two_pi);
  int bi = (int)floorf(pm * scale);
  return ((bi % NCP) + NCP) % NCP;   // identical mod logic to the GEMM's cc[]
}

// Deterministic stable counting-sort of rows by Catmull-Rom segment.
// One block, 256 threads x 32 contiguous rows each. Emits perm (ushort,
// sorted-pos -> orig row) and per-row-block {jlo, NJ} chunk windows.
__global__ void sort_rows(const float* __restrict__ phase,
                          unsigned short* __restrict__ perm,
                          int* __restrict__ blkinfo) {
  __shared__ int hist[256][NCP];
  __shared__ int segtot[NCP];
  __shared__ int cum[NCP + 1];
  __shared__ int thrbase[256][NCP];
  int t = (int)threadIdx.x;
  for (int s = 0; s < NCP; ++s) hist[t][s] = 0;
  for (int i = 0; i < 32; ++i) {
    int b = t * 32 + i;
    hist[t][seg_of(phase[b])]++;
  }
  __syncthreads();
  if (t < NCP) {
    int tot = 0;
    for (int tt = 0; tt < 256; ++tt) tot += hist[tt][t];
    segtot[t] = tot;
  }
  __syncthreads();
  if (t == 0) {
    cum[0] = 0;
    for (int s = 0; s < NCP; ++s) cum[s + 1] = cum[s] + segtot[s];
  }
  __syncthreads();
  for (int s = 0; s < NCP; ++s) {
    int p = 0;
    for (int tt = 0; tt < t; ++tt) p += hist[tt][s];
    thrbase[t][s] = cum[s] + p;
  }
  // stable ranked scatter (no atomics: deterministic)
  for (int i = 0; i < 32; ++i) {
    int b = t * 32 + i;
    int s = seg_of(phase[b]);
    int pos = thrbase[t][s]++;
    perm[pos] = (unsigned short)b;
  }
  __syncthreads();
  if (t < B_SZ / 256) {   // 32 row-blocks
    int start = t * 256, end = start + 255;
    int s0 = 0; while (s0 < NCP - 1 && cum[s0 + 1] <= start) ++s0;
    int s1 = 0; while (s1 < NCP - 1 && cum[s1 + 1] <= end) ++s1;
    int nj = s1 - s0 + 4; if (nj > NCP) nj = NCP;
    blkinfo[2 * t] = (s0 + NCP - 1) % NCP;   // jlo
    blkinfo[2 * t + 1] = nj;
  }
}

// x cast fused with the row permutation: xb[pos] = bf16(x[perm[pos]]).
// Same traffic as the old cvt; GEMM A-staging stays linear+coalesced.
__global__ void cast_x_perm(const float* __restrict__ x,
                            const unsigned short* __restrict__ perm,
                            unsigned short* __restrict__ xb) {
  int idx = blockIdx.x * blockDim.x + threadIdx.x;
  int stride = gridDim.x * blockDim.x;
  const int total = B_SZ * (I_SZ / 4);
  for (int i = idx; i < total; i += stride) {
    int pos = i >> 8;          // I_SZ/4 = 256 chunks per row
    int c = i & 255;
    int src = (int)perm[pos];
    float4 v = reinterpret_cast<const float4*>(x + (size_t)src * I_SZ)[c];
    ushort4 o;
    o.x = f2bf(v.x); o.y = f2bf(v.y); o.z = f2bf(v.z); o.w = f2bf(v.w);
    reinterpret_cast<ushort4*>(xb + (size_t)pos * I_SZ)[c] = o;
  }
}

__device__ __forceinline__ void gload_lds16(const void* g, void* l) {
  __builtin_amdgcn_global_load_lds(
      (const __attribute__((address_space(1))) void*)g,
      (__attribute__((address_space(3))) void*)l, 16, 0, 0);
}

#define BM 256
#define BN 128
#define BK 64
#define NBUF 3

// R12's verified body (114us champion: reg-dbuf fragments, 1 counted-vmcnt
// + 1 barrier per tile, ring-3 LDS-DMA w/ both-sides XOR swizzle, part[]
// AGPR chain folded per chunk) on SORTED rows: each block's 256 rows span
// <=2 adjacent segments, so only NJ in {4,5} of the 6 W chunks are needed
// -> 33% fewer FLOPs for pure blocks. Loop bound NJ*16 runtime; chunk =
// (jlo + t/16) mod 6 feeds only LDS/address indices (register arrays stay
// statically indexed, rule #20). Epilogue scatters rows via pblk[] (LDS).
__global__ __launch_bounds__(512, 1) void pfl_gemm(
    const unsigned short* __restrict__ xb,   // permuted rows
    const unsigned short* __restrict__ wb,
    const float* __restrict__ phase,
    const unsigned short* __restrict__ perm,
    const int* __restrict__ blkinfo,
    const float* __restrict__ bias,
    float* __restrict__ out) {
  __shared__ __align__(16) unsigned short Abuf[NBUF][BM * BK];  // 3x32 KB
  __shared__ __align__(16) unsigned short Bbuf[NBUF][BN * BK];  // 3x16 KB
  __shared__ __align__(16) float c4[NCP][BM];                   // 6 KB
  __shared__ int pblk[BM];                                      // 1 KB

  const int nbn = O_SZ / BN;  // 8
  int bid = (int)blockIdx.x;  // 256 blocks (divisible by 8)
  int swz = (bid & 7) * 32 + (bid >> 3);  // bijective XCD remap
  int rowblk = swz / nbn;
  int brow = rowblk * BM;
  int bcol = (swz % nbn) * BN;

  int tid = (int)threadIdx.x;
  int lane = tid & 63;
  int wid = tid >> 6;        // 0..7
  int wr = wid >> 1;         // 0..3 (M)
  int wc = wid & 1;          // 0..1 (N)

  int jlo = blkinfo[2 * rowblk];
  int NTb = blkinfo[2 * rowblk + 1] << 4;   // NJ*16 tiles

  // ---- Catmull-Rom coefficients (via perm gather) + pblk ----
  if (tid < BM) {
    int orow = (int)perm[brow + tid];
    pblk[tid] = orow;
    float ph = phase[orow];
    const float two_pi = 6.2831855f;
    float pm = fmodf(ph, two_pi);
    float pos = pm * (float)(6.0 / 6.283185307179586);
    float base = floorf(pos);
    int bi = (int)base;
    float t = pos - base;
    float t2 = t * t, t3 = t2 * t;
    float w0 = -0.5f * t + t2 - 0.5f * t3;
    float w1 = 1.0f - 2.5f * t2 + 1.5f * t3;
    float w2 = 0.5f * t + 2.0f * t2 - 1.5f * t3;
    float w3 = -0.5f * t2 + 0.5f * t3;
    float cc[NCP] = {0.f, 0.f, 0.f, 0.f, 0.f, 0.f};
    cc[((bi - 1) % NCP + NCP) % NCP] += w0;
    cc[(bi % NCP + NCP) % NCP]       += w1;
    cc[((bi + 1) % NCP + NCP) % NCP] += w2;
    cc[((bi + 2) % NCP + NCP) % NCP] += w3;
    for (int j = 0; j < NCP; ++j) c4[j][tid] = cc[j];
  }

  f32x4 acc[4][4];   // folded result (VALU-touched once per 16 tiles)
  f32x4 part[4][4];  // pure MFMA chain within a chunk (AGPR-resident)
#pragma unroll
  for (int m = 0; m < 4; ++m)
#pragma unroll
    for (int n = 0; n < 4; ++n) {
      acc[m][n] = (f32x4){0.f, 0.f, 0.f, 0.f};
      part[m][n] = (f32x4){0.f, 0.f, 0.f, 0.f};
    }

  // staging: lane l -> LDS row (8-group + l>>3), linear 16B slot (l&7);
  // global source column pre-swizzled (slot xor row&7), rule #21.
  int swzcol = ((lane & 7) ^ (lane >> 3)) * 8;
  const unsigned short* xsrc =
      xb + (size_t)(brow + wid * 8 + (lane >> 3)) * I_SZ + swzcol;
  const unsigned short* wsrc =
      wb + (size_t)(bcol + wid * 8 + (lane >> 3)) * I_SZ + swzcol;

  // read-side swizzled base: slot = chunk ^ (row&7); row&7 == lane&7 here
  int lbase = (lane & 15) * 128 + (((lane >> 4) ^ (lane & 7)) & 7) * 16;

  auto STAGE = [&](int t, int b) {   // 6 DMAs: 4 A + 2 B
    int ks = (t & 15) * 64;
    int cN = jlo + (t >> 4); if (cN >= NCP) cN -= NCP;
    const unsigned short* xs = xsrc + ks;
    const unsigned short* ws = wsrc + (size_t)cN * O_SZ * I_SZ + ks;
    unsigned short* Ad = &Abuf[b][(wid * 8) * BK];
    unsigned short* Bd = &Bbuf[b][(wid * 8) * BK];
#pragma unroll
    for (int p = 0; p < 4; ++p)
      gload_lds16(xs + (size_t)p * 64 * I_SZ, Ad + p * 64 * BK);
#pragma unroll
    for (int p = 0; p < 2; ++p)
      gload_lds16(ws + (size_t)p * 64 * I_SZ, Bd + p * 64 * BK);
  };

  // prologue: tiles 0,1 in flight (12 DMAs); tile 0 resident; c4 published
  STAGE(0, 0);
  STAGE(1, 1);
  asm volatile("s_waitcnt vmcnt(6)" ::: "memory");
  __builtin_amdgcn_sched_barrier(0);
  __syncthreads();

  int cur = 0;
  for (int t = 0; t < NTb; ++t) {
    const char* Ab = (const char*)&Abuf[cur][0];
    const char* Bb = (const char*)&Bbuf[cur][0];
    int st = cur + 2; if (st >= NBUF) st -= NBUF;

    // ---- kk=0 fragment reads ----
    bf16x8 af0[4], bf0[4], af1[4], bf1[4];
#pragma unroll
    for (int m = 0; m < 4; ++m)
      af0[m] = *reinterpret_cast<const bf16x8*>(
          Ab + (wr * 64 + m * 16) * 128 + lbase);
#pragma unroll
    for (int n = 0; n < 4; ++n)
      bf0[n] = *reinterpret_cast<const bf16x8*>(
          Bb + (wc * 64 + n * 16) * 128 + lbase);
    // ---- stage t+2 (vmcnt ops; do not disturb lgkm) ----
    if (t + 2 < NTb) STAGE(t + 2, st);
    asm volatile("s_waitcnt lgkmcnt(0)" ::: "memory");
    __builtin_amdgcn_sched_barrier(0);

    // ---- issue kk=1 reads: they fly under MFMA0 ----
#pragma unroll
    for (int m = 0; m < 4; ++m)
      af1[m] = *reinterpret_cast<const bf16x8*>(
          Ab + (wr * 64 + m * 16) * 128 + (lbase ^ 64));
#pragma unroll
    for (int n = 0; n < 4; ++n)
      bf1[n] = *reinterpret_cast<const bf16x8*>(
          Bb + (wc * 64 + n * 16) * 128 + (lbase ^ 64));
    __builtin_amdgcn_sched_barrier(0);  // pin kk1 issue before MFMA0

    __builtin_amdgcn_s_setprio(1);
#pragma unroll
    for (int m = 0; m < 4; ++m)
#pragma unroll
      for (int n = 0; n < 4; ++n)
        part[m][n] = __builtin_amdgcn_mfma_f32_16x16x32_bf16(
            af0[m], bf0[n], part[m][n], 0, 0, 0);
    __builtin_amdgcn_s_setprio(0);

    asm volatile("s_waitcnt lgkmcnt(0)" ::: "memory");  // kk1 frags landed
    __builtin_amdgcn_sched_barrier(0);

    __builtin_amdgcn_s_setprio(1);
#pragma unroll
    for (int m = 0; m < 4; ++m)
#pragma unroll
      for (int n = 0; n < 4; ++n)
        part[m][n] = __builtin_amdgcn_mfma_f32_16x16x32_bf16(
            af1[m], bf1[n], part[m][n], 0, 0, 0);
    __builtin_amdgcn_s_setprio(0);

    if ((t & 15) == 15) {  // chunk boundary: acc += c[row,chunk] * part
      int cj = jlo + (t >> 4); if (cj >= NCP) cj -= NCP;
#pragma unroll
      for (int m = 0; m < 4; ++m) {
        f32x4 cv = *reinterpret_cast<const f32x4*>(
            &c4[cj][wr * 64 + m * 16 + (lane >> 4) * 4]);
#pragma unroll
        for (int n = 0; n < 4; ++n) {
          acc[m][n] += cv * part[m][n];
          part[m][n] = (f32x4){0.f, 0.f, 0.f, 0.f};
        }
      }
    }

    // ---- tile boundary: counted vmcnt + SINGLE barrier ----
    if (t + 2 < NTb)
      asm volatile("s_waitcnt vmcnt(6)" ::: "memory");   // t+1 resident
    else
      asm volatile("s_waitcnt vmcnt(0)" ::: "memory");
    __builtin_amdgcn_sched_barrier(0);
    __builtin_amdgcn_s_barrier();
    ++cur; if (cur == NBUF) cur = 0;
  }

  // ---- epilogue: bias mix + scattered row store (f32) ----
#pragma unroll
  for (int n = 0; n < 4; ++n) {
    int col = bcol + wc * 64 + n * 16 + (lane & 15);
    float b6[NCP];
#pragma unroll
    for (int j = 0; j < NCP; ++j) b6[j] = bias[j * O_SZ + col];
#pragma unroll
    for (int m = 0; m < 4; ++m) {
#pragma unroll
      for (int r = 0; r < 4; ++r) {
        int rloc = wr * 64 + m * 16 + (lane >> 4) * 4 + r;
        float s = 0.f;
#pragma unroll
        for (int j = 0; j < NCP; ++j) s += c4[j][rloc] * b6[j];
        out[(size_t)pblk[rloc] * O_SZ + col] = acc[m][n][r] + s;
      }
    }
  }
}

extern "C" void kernel_launch(void* const* d_in, const int* in_sizes, int n_in,
                              void* d_out, int out_size, void* d_ws, size_t ws_size,
                              hipStream_t stream) {
  (void)in_sizes; (void)n_in; (void)out_size; (void)ws_size;
  const float* x     = (const float*)d_in[0];  // [B, I]
  const float* phase = (const float*)d_in[1];  // [B]
  const float* w     = (const float*)d_in[2];  // [C, O, I]
  const float* bias  = (const float*)d_in[3];  // [C, O]
  float* out = (float*)d_out;                  // [B, O] f32

  char* ws = (char*)d_ws;
  unsigned short* xb = (unsigned short*)ws;                          // 16 MB
  unsigned short* wb = (unsigned short*)(ws + (size_t)16 * 1024 * 1024);  // 12 MB
  unsigned short* perm = (unsigned short*)(ws + (size_t)28 * 1024 * 1024);  // 16 KB
  int* blkinfo = (int*)(ws + (size_t)28 * 1024 * 1024 + 16384);      // 256 B

  sort_rows<<<1, 256, 0, stream>>>(phase, perm, blkinfo);
  cast_x_perm<<<2048, 256, 0, stream>>>(x, perm, xb);
  cvt_f32_to_bf16<<<1536, 256, 0, stream>>>(w, wb, NCP * O_SZ * I_SZ / 4);

  dim3 grid((B_SZ / BM) * (O_SZ / BN));  // 32*8 = 256
  pfl_gemm<<<grid, 512, 0, stream>>>(xb, wb, phase, perm, blkinfo, bias, out);
}

// Round 19
// 116.608 us; speedup vs baseline: 2.1574x; 1.1673x over previous
//
#include <hip/hip_runtime.h>
#include <hip/hip_bf16.h>
#include <math.h>

#define B_SZ 8192
#define I_SZ 1024
#define O_SZ 1024
#define NCP  6

typedef __attribute__((ext_vector_type(8))) short bf16x8;
typedef __attribute__((ext_vector_type(4))) float f32x4;

__device__ __forceinline__ unsigned short f2bf(float f) {
  union { float f; unsigned int u; } v; v.f = f;
  unsigned int u = v.u;
  u += 0x7FFFu + ((u >> 16) & 1u);   // round-to-nearest-even
  return (unsigned short)(u >> 16);
}

__global__ void cvt_f32_to_bf16(const float* __restrict__ src,
                                unsigned short* __restrict__ dst, int n4) {
  int idx = blockIdx.x * blockDim.x + threadIdx.x;
  int stride = gridDim.x * blockDim.x;
  for (int i = idx; i < n4; i += stride) {
    float4 v = reinterpret_cast<const float4*>(src)[i];
    ushort4 o;
    o.x = f2bf(v.x); o.y = f2bf(v.y); o.z = f2bf(v.z); o.w = f2bf(v.w);
    reinterpret_cast<ushort4*>(dst)[i] = o;
  }
}

__device__ __forceinline__ int seg_of(float ph) {
  const float two_pi = 6.2831855f;
  const float scale = (float)(6.0 / 6.283185307179586);
  float pm = fmodf(ph, two_pi);
  int bi = (int)floorf(pm * scale);
  return ((bi % NCP) + NCP) % NCP;   // identical mod logic to the GEMM's cc[]
}

// Deterministic stable counting-sort of rows by Catmull-Rom segment.
// R18 rewrite: 1024 threads x 8 rows, Kogge-Stone inclusive scan (10 steps,
// all-LDS) -- replaces R17's O(t*6) serial LDS ranking loop that cost ~29us
// (latency-bound serial reads). All runtime-indexed per-thread arrays live
// in LDS (rule #20: reg arrays with runtime index spill to scratch).
__global__ __launch_bounds__(1024) void sort_rows(
    const float* __restrict__ phase,
    unsigned short* __restrict__ perm,
    int* __restrict__ blkinfo) {
  __shared__ int scanbuf[1024][NCP];  // 24 KB: hist -> inclusive prefix
  __shared__ int ownh[1024][NCP];     // 24 KB: own hist, then scatter base
  __shared__ int cum[NCP + 1];
  int t = (int)threadIdx.x;
  int segs[8];
#pragma unroll
  for (int s = 0; s < NCP; ++s) scanbuf[t][s] = 0;
#pragma unroll
  for (int i = 0; i < 8; ++i) {
    segs[i] = seg_of(phase[t * 8 + i]);
    scanbuf[t][segs[i]]++;
  }
#pragma unroll
  for (int s = 0; s < NCP; ++s) ownh[t][s] = scanbuf[t][s];
  __syncthreads();
  // Kogge-Stone inclusive scan over 1024 threads (6-int tuples)
  for (int d = 1; d < 1024; d <<= 1) {
    int add[NCP];
    if (t >= d) {
#pragma unroll
      for (int s = 0; s < NCP; ++s) add[s] = scanbuf[t - d][s];
    }
    __syncthreads();
    if (t >= d) {
#pragma unroll
      for (int s = 0; s < NCP; ++s) scanbuf[t][s] += add[s];
    }
    __syncthreads();
  }
  if (t == 0) {
    cum[0] = 0;
    for (int s = 0; s < NCP; ++s) cum[s + 1] = cum[s] + scanbuf[1023][s];
  }
  __syncthreads();
  // exclusive base for this thread, per segment (into ownh, LDS)
#pragma unroll
  for (int s = 0; s < NCP; ++s)
    ownh[t][s] = cum[s] + scanbuf[t][s] - ownh[t][s];
  // stable scatter: thread-major order == original row order
#pragma unroll
  for (int i = 0; i < 8; ++i) {
    int s = segs[i];
    perm[ownh[t][s]++] = (unsigned short)(t * 8 + i);
  }
  if (t < B_SZ / 256) {   // 32 row-blocks of the sorted array
    int start = t * 256, end = start + 255;
    int s0 = 0; while (s0 < NCP - 1 && cum[s0 + 1] <= start) ++s0;
    int s1 = 0; while (s1 < NCP - 1 && cum[s1 + 1] <= end) ++s1;
    int nj = s1 - s0 + 4; if (nj > NCP) nj = NCP;
    blkinfo[2 * t] = (s0 + NCP - 1) % NCP;   // jlo
    blkinfo[2 * t + 1] = nj;
  }
}

// x cast fused with the row permutation: xb[pos] = bf16(x[perm[pos]]).
// Wave reads stay within one source row (contiguous) -> coalesced.
__global__ void cast_x_perm(const float* __restrict__ x,
                            const unsigned short* __restrict__ perm,
                            unsigned short* __restrict__ xb) {
  int idx = blockIdx.x * blockDim.x + threadIdx.x;
  int stride = gridDim.x * blockDim.x;
  const int total = B_SZ * (I_SZ / 4);
  for (int i = idx; i < total; i += stride) {
    int pos = i >> 8;          // I_SZ/4 = 256 chunks per row
    int c = i & 255;
    int src = (int)perm[pos];
    float4 v = reinterpret_cast<const float4*>(x + (size_t)src * I_SZ)[c];
    ushort4 o;
    o.x = f2bf(v.x); o.y = f2bf(v.y); o.z = f2bf(v.z); o.w = f2bf(v.w);
    reinterpret_cast<ushort4*>(xb + (size_t)pos * I_SZ)[c] = o;
  }
}

__device__ __forceinline__ void gload_lds16(const void* g, void* l) {
  __builtin_amdgcn_global_load_lds(
      (const __attribute__((address_space(1))) void*)g,
      (__attribute__((address_space(3))) void*)l, 16, 0, 0);
}

#define BM 256
#define BN 128
#define BK 64
#define NBUF 3

// R12's verified body (reg-dbuf fragments, 1 counted-vmcnt + 1 barrier per
// tile, ring-3 LDS-DMA w/ both-sides XOR swizzle, part[] AGPR chain folded
// per chunk) on SORTED rows: each block's 256 rows span <=2 adjacent
// segments -> only NJ in {4,5} of 6 W chunks needed (avg ~4.2: 30% fewer
// FLOPs; measured 114 -> 93us in R17). Chunk index feeds only LDS/address
// paths; register arrays statically indexed (rule #20).
__global__ __launch_bounds__(512, 1) void pfl_gemm(
    const unsigned short* __restrict__ xb,   // permuted rows
    const unsigned short* __restrict__ wb,
    const float* __restrict__ phase,
    const unsigned short* __restrict__ perm,
    const int* __restrict__ blkinfo,
    const float* __restrict__ bias,
    float* __restrict__ out) {
  __shared__ __align__(16) unsigned short Abuf[NBUF][BM * BK];  // 3x32 KB
  __shared__ __align__(16) unsigned short Bbuf[NBUF][BN * BK];  // 3x16 KB
  __shared__ __align__(16) float c4[NCP][BM];                   // 6 KB
  __shared__ int pblk[BM];                                      // 1 KB

  const int nbn = O_SZ / BN;  // 8
  int bid = (int)blockIdx.x;  // 256 blocks (divisible by 8)
  int swz = (bid & 7) * 32 + (bid >> 3);  // bijective XCD remap
  int rowblk = swz / nbn;
  int brow = rowblk * BM;
  int bcol = (swz % nbn) * BN;

  int tid = (int)threadIdx.x;
  int lane = tid & 63;
  int wid = tid >> 6;        // 0..7
  int wr = wid >> 1;         // 0..3 (M)
  int wc = wid & 1;          // 0..1 (N)

  int jlo = blkinfo[2 * rowblk];
  int NTb = blkinfo[2 * rowblk + 1] << 4;   // NJ*16 tiles

  // ---- Catmull-Rom coefficients (via perm gather) + pblk ----
  if (tid < BM) {
    int orow = (int)perm[brow + tid];
    pblk[tid] = orow;
    float ph = phase[orow];
    const float two_pi = 6.2831855f;
    float pm = fmodf(ph, two_pi);
    float pos = pm * (float)(6.0 / 6.283185307179586);
    float base = floorf(pos);
    int bi = (int)base;
    float t = pos - base;
    float t2 = t * t, t3 = t2 * t;
    float w0 = -0.5f * t + t2 - 0.5f * t3;
    float w1 = 1.0f - 2.5f * t2 + 1.5f * t3;
    float w2 = 0.5f * t + 2.0f * t2 - 1.5f * t3;
    float w3 = -0.5f * t2 + 0.5f * t3;
    float cc[NCP] = {0.f, 0.f, 0.f, 0.f, 0.f, 0.f};
    cc[((bi - 1) % NCP + NCP) % NCP] += w0;
    cc[(bi % NCP + NCP) % NCP]       += w1;
    cc[((bi + 1) % NCP + NCP) % NCP] += w2;
    cc[((bi + 2) % NCP + NCP) % NCP] += w3;
    for (int j = 0; j < NCP; ++j) c4[j][tid] = cc[j];
  }

  f32x4 acc[4][4];   // folded result (VALU-touched once per 16 tiles)
  f32x4 part[4][4];  // pure MFMA chain within a chunk (AGPR-resident)
#pragma unroll
  for (int m = 0; m < 4; ++m)
#pragma unroll
    for (int n = 0; n < 4; ++n) {
      acc[m][n] = (f32x4){0.f, 0.f, 0.f, 0.f};
      part[m][n] = (f32x4){0.f, 0.f, 0.f, 0.f};
    }

  // staging: lane l -> LDS row (8-group + l>>3), linear 16B slot (l&7);
  // global source column pre-swizzled (slot xor row&7), rule #21.
  int swzcol = ((lane & 7) ^ (lane >> 3)) * 8;
  const unsigned short* xsrc =
      xb + (size_t)(brow + wid * 8 + (lane >> 3)) * I_SZ + swzcol;
  const unsigned short* wsrc =
      wb + (size_t)(bcol + wid * 8 + (lane >> 3)) * I_SZ + swzcol;

  // read-side swizzled base: slot = chunk ^ (row&7); row&7 == lane&7 here
  int lbase = (lane & 15) * 128 + (((lane >> 4) ^ (lane & 7)) & 7) * 16;

  auto STAGE = [&](int t, int b) {   // 6 DMAs: 4 A + 2 B
    int ks = (t & 15) * 64;
    int cN = jlo + (t >> 4); if (cN >= NCP) cN -= NCP;
    const unsigned short* xs = xsrc + ks;
    const unsigned short* ws = wsrc + (size_t)cN * O_SZ * I_SZ + ks;
    unsigned short* Ad = &Abuf[b][(wid * 8) * BK];
    unsigned short* Bd = &Bbuf[b][(wid * 8) * BK];
#pragma unroll
    for (int p = 0; p < 4; ++p)
      gload_lds16(xs + (size_t)p * 64 * I_SZ, Ad + p * 64 * BK);
#pragma unroll
    for (int p = 0; p < 2; ++p)
      gload_lds16(ws + (size_t)p * 64 * I_SZ, Bd + p * 64 * BK);
  };

  // prologue: tiles 0,1 in flight (12 DMAs); tile 0 resident; c4 published
  STAGE(0, 0);
  STAGE(1, 1);
  asm volatile("s_waitcnt vmcnt(6)" ::: "memory");
  __builtin_amdgcn_sched_barrier(0);
  __syncthreads();

  int cur = 0;
  for (int t = 0; t < NTb; ++t) {
    const char* Ab = (const char*)&Abuf[cur][0];
    const char* Bb = (const char*)&Bbuf[cur][0];
    int st = cur + 2; if (st >= NBUF) st -= NBUF;

    // ---- kk=0 fragment reads ----
    bf16x8 af0[4], bf0[4], af1[4], bf1[4];
#pragma unroll
    for (int m = 0; m < 4; ++m)
      af0[m] = *reinterpret_cast<const bf16x8*>(
          Ab + (wr * 64 + m * 16) * 128 + lbase);
#pragma unroll
    for (int n = 0; n < 4; ++n)
      bf0[n] = *reinterpret_cast<const bf16x8*>(
          Bb + (wc * 64 + n * 16) * 128 + lbase);
    // ---- stage t+2 (vmcnt ops; do not disturb lgkm) ----
    if (t + 2 < NTb) STAGE(t + 2, st);
    asm volatile("s_waitcnt lgkmcnt(0)" ::: "memory");
    __builtin_amdgcn_sched_barrier(0);

    // ---- issue kk=1 reads: they fly under MFMA0 ----
#pragma unroll
    for (int m = 0; m < 4; ++m)
      af1[m] = *reinterpret_cast<const bf16x8*>(
          Ab + (wr * 64 + m * 16) * 128 + (lbase ^ 64));
#pragma unroll
    for (int n = 0; n < 4; ++n)
      bf1[n] = *reinterpret_cast<const bf16x8*>(
          Bb + (wc * 64 + n * 16) * 128 + (lbase ^ 64));
    __builtin_amdgcn_sched_barrier(0);  // pin kk1 issue before MFMA0

    __builtin_amdgcn_s_setprio(1);
#pragma unroll
    for (int m = 0; m < 4; ++m)
#pragma unroll
      for (int n = 0; n < 4; ++n)
        part[m][n] = __builtin_amdgcn_mfma_f32_16x16x32_bf16(
            af0[m], bf0[n], part[m][n], 0, 0, 0);
    __builtin_amdgcn_s_setprio(0);

    asm volatile("s_waitcnt lgkmcnt(0)" ::: "memory");  // kk1 frags landed
    __builtin_amdgcn_sched_barrier(0);

    __builtin_amdgcn_s_setprio(1);
#pragma unroll
    for (int m = 0; m < 4; ++m)
#pragma unroll
      for (int n = 0; n < 4; ++n)
        part[m][n] = __builtin_amdgcn_mfma_f32_16x16x32_bf16(
            af1[m], bf1[n], part[m][n], 0, 0, 0);
    __builtin_amdgcn_s_setprio(0);

    if ((t & 15) == 15) {  // chunk boundary: acc += c[row,chunk] * part
      int cj = jlo + (t >> 4); if (cj >= NCP) cj -= NCP;
#pragma unroll
      for (int m = 0; m < 4; ++m) {
        f32x4 cv = *reinterpret_cast<const f32x4*>(
            &c4[cj][wr * 64 + m * 16 + (lane >> 4) * 4]);
#pragma unroll
        for (int n = 0; n < 4; ++n) {
          acc[m][n] += cv * part[m][n];
          part[m][n] = (f32x4){0.f, 0.f, 0.f, 0.f};
        }
      }
    }

    // ---- tile boundary: counted vmcnt + SINGLE barrier ----
    if (t + 2 < NTb)
      asm volatile("s_waitcnt vmcnt(6)" ::: "memory");   // t+1 resident
    else
      asm volatile("s_waitcnt vmcnt(0)" ::: "memory");
    __builtin_amdgcn_sched_barrier(0);
    __builtin_amdgcn_s_barrier();
    ++cur; if (cur == NBUF) cur = 0;
  }

  // ---- epilogue: bias mix + scattered row store (f32) ----
#pragma unroll
  for (int n = 0; n < 4; ++n) {
    int col = bcol + wc * 64 + n * 16 + (lane & 15);
    float b6[NCP];
#pragma unroll
    for (int j = 0; j < NCP; ++j) b6[j] = bias[j * O_SZ + col];
#pragma unroll
    for (int m = 0; m < 4; ++m) {
#pragma unroll
      for (int r = 0; r < 4; ++r) {
        int rloc = wr * 64 + m * 16 + (lane >> 4) * 4 + r;
        float s = 0.f;
#pragma unroll
        for (int j = 0; j < NCP; ++j) s += c4[j][rloc] * b6[j];
        out[(size_t)pblk[rloc] * O_SZ + col] = acc[m][n][r] + s;
      }
    }
  }
}

extern "C" void kernel_launch(void* const* d_in, const int* in_sizes, int n_in,
                              void* d_out, int out_size, void* d_ws, size_t ws_size,
                              hipStream_t stream) {
  (void)in_sizes; (void)n_in; (void)out_size; (void)ws_size;
  const float* x     = (const float*)d_in[0];  // [B, I]
  const float* phase = (const float*)d_in[1];  // [B]
  const float* w     = (const float*)d_in[2];  // [C, O, I]
  const float* bias  = (const float*)d_in[3];  // [C, O]
  float* out = (float*)d_out;                  // [B, O] f32

  char* ws = (char*)d_ws;
  unsigned short* xb = (unsigned short*)ws;                          // 16 MB
  unsigned short* wb = (unsigned short*)(ws + (size_t)16 * 1024 * 1024);  // 12 MB
  unsigned short* perm = (unsigned short*)(ws + (size_t)28 * 1024 * 1024);  // 16 KB
  int* blkinfo = (int*)(ws + (size_t)28 * 1024 * 1024 + 16384);      // 256 B

  sort_rows<<<1, 1024, 0, stream>>>(phase, perm, blkinfo);
  cast_x_perm<<<2048, 256, 0, stream>>>(x, perm, xb);
  cvt_f32_to_bf16<<<1536, 256, 0, stream>>>(w, wb, NCP * O_SZ * I_SZ / 4);

  dim3 grid((B_SZ / BM) * (O_SZ / BN));  // 32*8 = 256
  pfl_gemm<<<grid, 512, 0, stream>>>(xb, wb, phase, perm, blkinfo, bias, out);
}

// Round 20
// 113.133 us; speedup vs baseline: 2.2237x; 1.0307x over previous
//
#include <hip/hip_runtime.h>
#include <hip/hip_bf16.h>
#include <math.h>

#define B_SZ 8192
#define I_SZ 1024
#define O_SZ 1024
#define NCP  6

typedef __attribute__((ext_vector_type(8))) short bf16x8;
typedef __attribute__((ext_vector_type(4))) float f32x4;

__device__ __forceinline__ unsigned short f2bf(float f) {
  union { float f; unsigned int u; } v; v.f = f;
  unsigned int u = v.u;
  u += 0x7FFFu + ((u >> 16) & 1u);   // round-to-nearest-even
  return (unsigned short)(u >> 16);
}

__device__ __forceinline__ int seg_of(float ph) {
  const float two_pi = 6.2831855f;
  const float scale = (float)(6.0 / 6.283185307179586);
  float pm = fmodf(ph, two_pi);
  int bi = (int)floorf(pm * scale);
  return ((bi % NCP) + NCP) % NCP;   // identical mod logic to the GEMM's cc[]
}

// FUSED prep: blocks 0..griddim-2 cast W f32->bf16 (grid-stride);
// the LAST block does the deterministic counting-sort of rows by segment
// (R18's verified 1024-thread Kogge-Stone scan). No cross-block deps;
// sort (~3us) hides under the W cast (~6us) instead of serializing.
__global__ __launch_bounds__(1024) void prep_w_sort(
    const float* __restrict__ w, unsigned short* __restrict__ wb, int n4,
    const float* __restrict__ phase,
    unsigned short* __restrict__ perm,
    int* __restrict__ blkinfo) {
  __shared__ int scanbuf[1024][NCP];  // 24 KB
  __shared__ int ownh[1024][NCP];     // 24 KB
  __shared__ int cum[NCP + 1];
  int t = (int)threadIdx.x;

  if ((int)blockIdx.x != (int)gridDim.x - 1) {
    // ---- W cast (blocks 0..N-2) ----
    int idx = blockIdx.x * 1024 + t;
    int stride = ((int)gridDim.x - 1) * 1024;
    for (int i = idx; i < n4; i += stride) {
      float4 v = reinterpret_cast<const float4*>(w)[i];
      ushort4 o;
      o.x = f2bf(v.x); o.y = f2bf(v.y); o.z = f2bf(v.z); o.w = f2bf(v.w);
      reinterpret_cast<ushort4*>(wb)[i] = o;
    }
    return;
  }

  // ---- sort block (last) ----
  int segs[8];
#pragma unroll
  for (int s = 0; s < NCP; ++s) scanbuf[t][s] = 0;
#pragma unroll
  for (int i = 0; i < 8; ++i) {
    segs[i] = seg_of(phase[t * 8 + i]);
    scanbuf[t][segs[i]]++;
  }
#pragma unroll
  for (int s = 0; s < NCP; ++s) ownh[t][s] = scanbuf[t][s];
  __syncthreads();
  for (int d = 1; d < 1024; d <<= 1) {   // Kogge-Stone inclusive scan
    int add[NCP];
    if (t >= d) {
#pragma unroll
      for (int s = 0; s < NCP; ++s) add[s] = scanbuf[t - d][s];
    }
    __syncthreads();
    if (t >= d) {
#pragma unroll
      for (int s = 0; s < NCP; ++s) scanbuf[t][s] += add[s];
    }
    __syncthreads();
  }
  if (t == 0) {
    cum[0] = 0;
    for (int s = 0; s < NCP; ++s) cum[s + 1] = cum[s] + scanbuf[1023][s];
  }
  __syncthreads();
#pragma unroll
  for (int s = 0; s < NCP; ++s)
    ownh[t][s] = cum[s] + scanbuf[t][s] - ownh[t][s];
#pragma unroll
  for (int i = 0; i < 8; ++i) {   // stable scatter (original row order)
    int s = segs[i];
    perm[ownh[t][s]++] = (unsigned short)(t * 8 + i);
  }
  if (t < B_SZ / 256) {   // 32 row-blocks of the sorted array
    int start = t * 256, end = start + 255;
    int s0 = 0; while (s0 < NCP - 1 && cum[s0 + 1] <= start) ++s0;
    int s1 = 0; while (s1 < NCP - 1 && cum[s1 + 1] <= end) ++s1;
    int nj = s1 - s0 + 4; if (nj > NCP) nj = NCP;
    blkinfo[2 * t] = (s0 + NCP - 1) % NCP;   // jlo
    blkinfo[2 * t + 1] = nj;
  }
}

// x cast fused with the row permutation: xb[pos] = bf16(x[perm[pos]]).
// Wave reads stay within one source row (contiguous) -> coalesced.
__global__ void cast_x_perm(const float* __restrict__ x,
                            const unsigned short* __restrict__ perm,
                            unsigned short* __restrict__ xb) {
  int idx = blockIdx.x * blockDim.x + threadIdx.x;
  int stride = gridDim.x * blockDim.x;
  const int total = B_SZ * (I_SZ / 4);
  for (int i = idx; i < total; i += stride) {
    int pos = i >> 8;          // I_SZ/4 = 256 chunks per row
    int c = i & 255;
    int src = (int)perm[pos];
    float4 v = reinterpret_cast<const float4*>(x + (size_t)src * I_SZ)[c];
    ushort4 o;
    o.x = f2bf(v.x); o.y = f2bf(v.y); o.z = f2bf(v.z); o.w = f2bf(v.w);
    reinterpret_cast<ushort4*>(xb + (size_t)pos * I_SZ)[c] = o;
  }
}

__device__ __forceinline__ void gload_lds16(const void* g, void* l) {
  __builtin_amdgcn_global_load_lds(
      (const __attribute__((address_space(1))) void*)g,
      (__attribute__((address_space(3))) void*)l, 16, 0, 0);
}

#define BM 256
#define BN 128
#define BK 64
#define NBUF 3

// R12's verified body (reg-dbuf fragments, 1 counted-vmcnt + 1 barrier per
// tile, ring-3 LDS-DMA w/ both-sides XOR swizzle, part[] AGPR chain folded
// per chunk) on SORTED rows: each block's 256 rows span <=2 adjacent
// segments -> only NJ in {4,5} of 6 W chunks needed (avg ~4.2; measured
// 114 -> 93us). Chunk index feeds only LDS/address paths; register arrays
// statically indexed (rule #20). BYTE-IDENTICAL to R19's verified GEMM.
__global__ __launch_bounds__(512, 1) void pfl_gemm(
    const unsigned short* __restrict__ xb,   // permuted rows
    const unsigned short* __restrict__ wb,
    const float* __restrict__ phase,
    const unsigned short* __restrict__ perm,
    const int* __restrict__ blkinfo,
    const float* __restrict__ bias,
    float* __restrict__ out) {
  __shared__ __align__(16) unsigned short Abuf[NBUF][BM * BK];  // 3x32 KB
  __shared__ __align__(16) unsigned short Bbuf[NBUF][BN * BK];  // 3x16 KB
  __shared__ __align__(16) float c4[NCP][BM];                   // 6 KB
  __shared__ int pblk[BM];                                      // 1 KB

  const int nbn = O_SZ / BN;  // 8
  int bid = (int)blockIdx.x;  // 256 blocks (divisible by 8)
  int swz = (bid & 7) * 32 + (bid >> 3);  // bijective XCD remap
  int rowblk = swz / nbn;
  int brow = rowblk * BM;
  int bcol = (swz % nbn) * BN;

  int tid = (int)threadIdx.x;
  int lane = tid & 63;
  int wid = tid >> 6;        // 0..7
  int wr = wid >> 1;         // 0..3 (M)
  int wc = wid & 1;          // 0..1 (N)

  int jlo = blkinfo[2 * rowblk];
  int NTb = blkinfo[2 * rowblk + 1] << 4;   // NJ*16 tiles

  // ---- Catmull-Rom coefficients (via perm gather) + pblk ----
  if (tid < BM) {
    int orow = (int)perm[brow + tid];
    pblk[tid] = orow;
    float ph = phase[orow];
    const float two_pi = 6.2831855f;
    float pm = fmodf(ph, two_pi);
    float pos = pm * (float)(6.0 / 6.283185307179586);
    float base = floorf(pos);
    int bi = (int)base;
    float t = pos - base;
    float t2 = t * t, t3 = t2 * t;
    float w0 = -0.5f * t + t2 - 0.5f * t3;
    float w1 = 1.0f - 2.5f * t2 + 1.5f * t3;
    float w2 = 0.5f * t + 2.0f * t2 - 1.5f * t3;
    float w3 = -0.5f * t2 + 0.5f * t3;
    float cc[NCP] = {0.f, 0.f, 0.f, 0.f, 0.f, 0.f};
    cc[((bi - 1) % NCP + NCP) % NCP] += w0;
    cc[(bi % NCP + NCP) % NCP]       += w1;
    cc[((bi + 1) % NCP + NCP) % NCP] += w2;
    cc[((bi + 2) % NCP + NCP) % NCP] += w3;
    for (int j = 0; j < NCP; ++j) c4[j][tid] = cc[j];
  }

  f32x4 acc[4][4];   // folded result (VALU-touched once per 16 tiles)
  f32x4 part[4][4];  // pure MFMA chain within a chunk (AGPR-resident)
#pragma unroll
  for (int m = 0; m < 4; ++m)
#pragma unroll
    for (int n = 0; n < 4; ++n) {
      acc[m][n] = (f32x4){0.f, 0.f, 0.f, 0.f};
      part[m][n] = (f32x4){0.f, 0.f, 0.f, 0.f};
    }

  // staging: lane l -> LDS row (8-group + l>>3), linear 16B slot (l&7);
  // global source column pre-swizzled (slot xor row&7), rule #21.
  int swzcol = ((lane & 7) ^ (lane >> 3)) * 8;
  const unsigned short* xsrc =
      xb + (size_t)(brow + wid * 8 + (lane >> 3)) * I_SZ + swzcol;
  const unsigned short* wsrc =
      wb + (size_t)(bcol + wid * 8 + (lane >> 3)) * I_SZ + swzcol;

  // read-side swizzled base: slot = chunk ^ (row&7); row&7 == lane&7 here
  int lbase = (lane & 15) * 128 + (((lane >> 4) ^ (lane & 7)) & 7) * 16;

  auto STAGE = [&](int t, int b) {   // 6 DMAs: 4 A + 2 B
    int ks = (t & 15) * 64;
    int cN = jlo + (t >> 4); if (cN >= NCP) cN -= NCP;
    const unsigned short* xs = xsrc + ks;
    const unsigned short* ws = wsrc + (size_t)cN * O_SZ * I_SZ + ks;
    unsigned short* Ad = &Abuf[b][(wid * 8) * BK];
    unsigned short* Bd = &Bbuf[b][(wid * 8) * BK];
#pragma unroll
    for (int p = 0; p < 4; ++p)
      gload_lds16(xs + (size_t)p * 64 * I_SZ, Ad + p * 64 * BK);
#pragma unroll
    for (int p = 0; p < 2; ++p)
      gload_lds16(ws + (size_t)p * 64 * I_SZ, Bd + p * 64 * BK);
  };

  // prologue: tiles 0,1 in flight (12 DMAs); tile 0 resident; c4 published
  STAGE(0, 0);
  STAGE(1, 1);
  asm volatile("s_waitcnt vmcnt(6)" ::: "memory");
  __builtin_amdgcn_sched_barrier(0);
  __syncthreads();

  int cur = 0;
  for (int t = 0; t < NTb; ++t) {
    const char* Ab = (const char*)&Abuf[cur][0];
    const char* Bb = (const char*)&Bbuf[cur][0];
    int st = cur + 2; if (st >= NBUF) st -= NBUF;

    // ---- kk=0 fragment reads ----
    bf16x8 af0[4], bf0[4], af1[4], bf1[4];
#pragma unroll
    for (int m = 0; m < 4; ++m)
      af0[m] = *reinterpret_cast<const bf16x8*>(
          Ab + (wr * 64 + m * 16) * 128 + lbase);
#pragma unroll
    for (int n = 0; n < 4; ++n)
      bf0[n] = *reinterpret_cast<const bf16x8*>(
          Bb + (wc * 64 + n * 16) * 128 + lbase);
    // ---- stage t+2 (vmcnt ops; do not disturb lgkm) ----
    if (t + 2 < NTb) STAGE(t + 2, st);
    asm volatile("s_waitcnt lgkmcnt(0)" ::: "memory");
    __builtin_amdgcn_sched_barrier(0);

    // ---- issue kk=1 reads: they fly under MFMA0 ----
#pragma unroll
    for (int m = 0; m < 4; ++m)
      af1[m] = *reinterpret_cast<const bf16x8*>(
          Ab + (wr * 64 + m * 16) * 128 + (lbase ^ 64));
#pragma unroll
    for (int n = 0; n < 4; ++n)
      bf1[n] = *reinterpret_cast<const bf16x8*>(
          Bb + (wc * 64 + n * 16) * 128 + (lbase ^ 64));
    __builtin_amdgcn_sched_barrier(0);  // pin kk1 issue before MFMA0

    __builtin_amdgcn_s_setprio(1);
#pragma unroll
    for (int m = 0; m < 4; ++m)
#pragma unroll
      for (int n = 0; n < 4; ++n)
        part[m][n] = __builtin_amdgcn_mfma_f32_16x16x32_bf16(
            af0[m], bf0[n], part[m][n], 0, 0, 0);
    __builtin_amdgcn_s_setprio(0);

    asm volatile("s_waitcnt lgkmcnt(0)" ::: "memory");  // kk1 frags landed
    __builtin_amdgcn_sched_barrier(0);

    __builtin_amdgcn_s_setprio(1);
#pragma unroll
    for (int m = 0; m < 4; ++m)
#pragma unroll
      for (int n = 0; n < 4; ++n)
        part[m][n] = __builtin_amdgcn_mfma_f32_16x16x32_bf16(
            af1[m], bf1[n], part[m][n], 0, 0, 0);
    __builtin_amdgcn_s_setprio(0);

    if ((t & 15) == 15) {  // chunk boundary: acc += c[row,chunk] * part
      int cj = jlo + (t >> 4); if (cj >= NCP) cj -= NCP;
#pragma unroll
      for (int m = 0; m < 4; ++m) {
        f32x4 cv = *reinterpret_cast<const f32x4*>(
            &c4[cj][wr * 64 + m * 16 + (lane >> 4) * 4]);
#pragma unroll
        for (int n = 0; n < 4; ++n) {
          acc[m][n] += cv * part[m][n];
          part[m][n] = (f32x4){0.f, 0.f, 0.f, 0.f};
        }
      }
    }

    // ---- tile boundary: counted vmcnt + SINGLE barrier ----
    if (t + 2 < NTb)
      asm volatile("s_waitcnt vmcnt(6)" ::: "memory");   // t+1 resident
    else
      asm volatile("s_waitcnt vmcnt(0)" ::: "memory");
    __builtin_amdgcn_sched_barrier(0);
    __builtin_amdgcn_s_barrier();
    ++cur; if (cur == NBUF) cur = 0;
  }

  // ---- epilogue: bias mix + scattered row store (f32) ----
#pragma unroll
  for (int n = 0; n < 4; ++n) {
    int col = bcol + wc * 64 + n * 16 + (lane & 15);
    float b6[NCP];
#pragma unroll
    for (int j = 0; j < NCP; ++j) b6[j] = bias[j * O_SZ + col];
#pragma unroll
    for (int m = 0; m < 4; ++m) {
#pragma unroll
      for (int r = 0; r < 4; ++r) {
        int rloc = wr * 64 + m * 16 + (lane >> 4) * 4 + r;
        float s = 0.f;
#pragma unroll
        for (int j = 0; j < NCP; ++j) s += c4[j][rloc] * b6[j];
        out[(size_t)pblk[rloc] * O_SZ + col] = acc[m][n][r] + s;
      }
    }
  }
}

extern "C" void kernel_launch(void* const* d_in, const int* in_sizes, int n_in,
                              void* d_out, int out_size, void* d_ws, size_t ws_size,
                              hipStream_t stream) {
  (void)in_sizes; (void)n_in; (void)out_size; (void)ws_size;
  const float* x     = (const float*)d_in[0];  // [B, I]
  const float* phase = (const float*)d_in[1];  // [B]
  const float* w     = (const float*)d_in[2];  // [C, O, I]
  const float* bias  = (const float*)d_in[3];  // [C, O]
  float* out = (float*)d_out;                  // [B, O] f32

  char* ws = (char*)d_ws;
  unsigned short* xb = (unsigned short*)ws;                          // 16 MB
  unsigned short* wb = (unsigned short*)(ws + (size_t)16 * 1024 * 1024);  // 12 MB
  unsigned short* perm = (unsigned short*)(ws + (size_t)28 * 1024 * 1024);  // 16 KB
  int* blkinfo = (int*)(ws + (size_t)28 * 1024 * 1024 + 16384);      // 256 B

  // fused: 768 cast blocks + 1 sort block (last)
  prep_w_sort<<<769, 1024, 0, stream>>>(w, wb, NCP * O_SZ * I_SZ / 4,
                                        phase, perm, blkinfo);
  cast_x_perm<<<2048, 256, 0, stream>>>(x, perm, xb);

  dim3 grid((B_SZ / BM) * (O_SZ / BN));  // 32*8 = 256
  pfl_gemm<<<grid, 512, 0, stream>>>(xb, wb, phase, perm, blkinfo, bias, out);
}

// Round 21
// 110.757 us; speedup vs baseline: 2.2714x; 1.0214x over previous
//
#include <hip/hip_runtime.h>
#include <hip/hip_bf16.h>
#include <math.h>

#define B_SZ 8192
#define I_SZ 1024
#define O_SZ 1024
#define NCP  6

typedef __attribute__((ext_vector_type(8))) short bf16x8;
typedef __attribute__((ext_vector_type(4))) float f32x4;

__device__ __forceinline__ unsigned short f2bf(float f) {
  union { float f; unsigned int u; } v; v.f = f;
  unsigned int u = v.u;
  u += 0x7FFFu + ((u >> 16) & 1u);   // round-to-nearest-even
  return (unsigned short)(u >> 16);
}

__device__ __forceinline__ int seg_of(float ph) {
  const float two_pi = 6.2831855f;
  const float scale = (float)(6.0 / 6.283185307179586);
  float pm = fmodf(ph, two_pi);
  int bi = (int)floorf(pm * scale);
  return ((bi % NCP) + NCP) % NCP;   // identical mod logic to the GEMM's cc[]
}

// SINGLE fused prep kernel:
//   blocks 0..1023    : cast x f32->bf16 (original row order -- no perm dep!)
//   blocks 1024..2047 : cast W f32->bf16
//   block  2048       : deterministic counting-sort of rows by segment
//                       (R18's verified 1024-thread Kogge-Stone scan)
// The GEMM reads A through perm-derived per-lane bases, so the x cast no
// longer depends on the sort -- all three roles run concurrently and the
// sort (~3us) hides under the ~13us of casts. Launches: 3 -> 2.
__global__ __launch_bounds__(1024) void prep_all(
    const float* __restrict__ x, unsigned short* __restrict__ xb,
    const float* __restrict__ w, unsigned short* __restrict__ wb,
    const float* __restrict__ phase,
    unsigned short* __restrict__ perm,
    int* __restrict__ blkinfo) {
  __shared__ int scanbuf[1024][NCP];  // 24 KB (sort block only)
  __shared__ int ownh[1024][NCP];     // 24 KB
  __shared__ int cum[NCP + 1];
  int t = (int)threadIdx.x;
  int b = (int)blockIdx.x;

  if (b < 1024) {            // ---- x cast ----
    const int n4 = B_SZ * I_SZ / 4;
    int idx = b * 1024 + t;
    for (int i = idx; i < n4; i += 1024 * 1024) {
      float4 v = reinterpret_cast<const float4*>(x)[i];
      ushort4 o;
      o.x = f2bf(v.x); o.y = f2bf(v.y); o.z = f2bf(v.z); o.w = f2bf(v.w);
      reinterpret_cast<ushort4*>(xb)[i] = o;
    }
    return;
  }
  if (b < 2048) {            // ---- W cast ----
    const int n4 = NCP * O_SZ * I_SZ / 4;
    int idx = (b - 1024) * 1024 + t;
    for (int i = idx; i < n4; i += 1024 * 1024) {
      float4 v = reinterpret_cast<const float4*>(w)[i];
      ushort4 o;
      o.x = f2bf(v.x); o.y = f2bf(v.y); o.z = f2bf(v.z); o.w = f2bf(v.w);
      reinterpret_cast<ushort4*>(wb)[i] = o;
    }
    return;
  }

  // ---- sort block ----
  int segs[8];
#pragma unroll
  for (int s = 0; s < NCP; ++s) scanbuf[t][s] = 0;
#pragma unroll
  for (int i = 0; i < 8; ++i) {
    segs[i] = seg_of(phase[t * 8 + i]);
    scanbuf[t][segs[i]]++;
  }
#pragma unroll
  for (int s = 0; s < NCP; ++s) ownh[t][s] = scanbuf[t][s];
  __syncthreads();
  for (int d = 1; d < 1024; d <<= 1) {   // Kogge-Stone inclusive scan
    int add[NCP];
    if (t >= d) {
#pragma unroll
      for (int s = 0; s < NCP; ++s) add[s] = scanbuf[t - d][s];
    }
    __syncthreads();
    if (t >= d) {
#pragma unroll
      for (int s = 0; s < NCP; ++s) scanbuf[t][s] += add[s];
    }
    __syncthreads();
  }
  if (t == 0) {
    cum[0] = 0;
    for (int s = 0; s < NCP; ++s) cum[s + 1] = cum[s] + scanbuf[1023][s];
  }
  __syncthreads();
#pragma unroll
  for (int s = 0; s < NCP; ++s)
    ownh[t][s] = cum[s] + scanbuf[t][s] - ownh[t][s];
#pragma unroll
  for (int i = 0; i < 8; ++i) {   // stable scatter (original row order)
    int s = segs[i];
    perm[ownh[t][s]++] = (unsigned short)(t * 8 + i);
  }
  if (t < B_SZ / 256) {   // 32 row-blocks of the sorted array
    int start = t * 256, end = start + 255;
    int s0 = 0; while (s0 < NCP - 1 && cum[s0 + 1] <= start) ++s0;
    int s1 = 0; while (s1 < NCP - 1 && cum[s1 + 1] <= end) ++s1;
    int nj = s1 - s0 + 4; if (nj > NCP) nj = NCP;
    blkinfo[2 * t] = (s0 + NCP - 1) % NCP;   // jlo
    blkinfo[2 * t + 1] = nj;
  }
}

__device__ __forceinline__ void gload_lds16(const void* g, void* l) {
  __builtin_amdgcn_global_load_lds(
      (const __attribute__((address_space(1))) void*)g,
      (__attribute__((address_space(3))) void*)l, 16, 0, 0);
}

#define BM 256
#define BN 128
#define BK 64
#define NBUF 3

// R20's verified GEMM (93us) with ONE change: A is staged from the
// ORIGINAL-order xb through perm-derived per-lane row bases (xsP0..3,
// computed once -- static names per rule #20). Transaction-neutral: the 8
// rows per A-DMA were already 2KB apart (8 separate 128B transactions),
// so permuted rows cost the same. W path, swizzle, vmcnt ledger (6 DMAs/
// tile, vmcnt(6)), per-chunk fold, epilogue pblk scatter: byte-identical.
__global__ __launch_bounds__(512, 1) void pfl_gemm(
    const unsigned short* __restrict__ xb,   // ORIGINAL row order
    const unsigned short* __restrict__ wb,
    const float* __restrict__ phase,
    const unsigned short* __restrict__ perm,
    const int* __restrict__ blkinfo,
    const float* __restrict__ bias,
    float* __restrict__ out) {
  __shared__ __align__(16) unsigned short Abuf[NBUF][BM * BK];  // 3x32 KB
  __shared__ __align__(16) unsigned short Bbuf[NBUF][BN * BK];  // 3x16 KB
  __shared__ __align__(16) float c4[NCP][BM];                   // 6 KB
  __shared__ int pblk[BM];                                      // 1 KB

  const int nbn = O_SZ / BN;  // 8
  int bid = (int)blockIdx.x;  // 256 blocks (divisible by 8)
  int swz = (bid & 7) * 32 + (bid >> 3);  // bijective XCD remap
  int rowblk = swz / nbn;
  int brow = rowblk * BM;
  int bcol = (swz % nbn) * BN;

  int tid = (int)threadIdx.x;
  int lane = tid & 63;
  int wid = tid >> 6;        // 0..7
  int wr = wid >> 1;         // 0..3 (M)
  int wc = wid & 1;          // 0..1 (N)

  int jlo = blkinfo[2 * rowblk];
  int NTb = blkinfo[2 * rowblk + 1] << 4;   // NJ*16 tiles

  // ---- Catmull-Rom coefficients (via perm gather) + pblk ----
  if (tid < BM) {
    int orow = (int)perm[brow + tid];
    pblk[tid] = orow;
    float ph = phase[orow];
    const float two_pi = 6.2831855f;
    float pm = fmodf(ph, two_pi);
    float pos = pm * (float)(6.0 / 6.283185307179586);
    float base = floorf(pos);
    int bi = (int)base;
    float t = pos - base;
    float t2 = t * t, t3 = t2 * t;
    float w0 = -0.5f * t + t2 - 0.5f * t3;
    float w1 = 1.0f - 2.5f * t2 + 1.5f * t3;
    float w2 = 0.5f * t + 2.0f * t2 - 1.5f * t3;
    float w3 = -0.5f * t2 + 0.5f * t3;
    float cc[NCP] = {0.f, 0.f, 0.f, 0.f, 0.f, 0.f};
    cc[((bi - 1) % NCP + NCP) % NCP] += w0;
    cc[(bi % NCP + NCP) % NCP]       += w1;
    cc[((bi + 1) % NCP + NCP) % NCP] += w2;
    cc[((bi + 2) % NCP + NCP) % NCP] += w3;
    for (int j = 0; j < NCP; ++j) c4[j][tid] = cc[j];
  }

  f32x4 acc[4][4];   // folded result (VALU-touched once per 16 tiles)
  f32x4 part[4][4];  // pure MFMA chain within a chunk (AGPR-resident)
#pragma unroll
  for (int m = 0; m < 4; ++m)
#pragma unroll
    for (int n = 0; n < 4; ++n) {
      acc[m][n] = (f32x4){0.f, 0.f, 0.f, 0.f};
      part[m][n] = (f32x4){0.f, 0.f, 0.f, 0.f};
    }

  // staging: lane l -> LDS row (8-group + l>>3), linear 16B slot (l&7);
  // global source column pre-swizzled (slot xor row&7), rule #21.
  int swzcol = ((lane & 7) ^ (lane >> 3)) * 8;
  // A: per-lane PERMUTED row bases, one per 64-row group (computed once;
  // the perm[] loads retire before STAGE issues -- address dependency).
  int r0 = brow + wid * 8 + (lane >> 3);
  const unsigned short* xsP0 = xb + (size_t)perm[r0      ] * I_SZ + swzcol;
  const unsigned short* xsP1 = xb + (size_t)perm[r0 +  64] * I_SZ + swzcol;
  const unsigned short* xsP2 = xb + (size_t)perm[r0 + 128] * I_SZ + swzcol;
  const unsigned short* xsP3 = xb + (size_t)perm[r0 + 192] * I_SZ + swzcol;
  const unsigned short* wsrc =
      wb + (size_t)(bcol + wid * 8 + (lane >> 3)) * I_SZ + swzcol;

  // read-side swizzled base: slot = chunk ^ (row&7); row&7 == lane&7 here
  int lbase = (lane & 15) * 128 + (((lane >> 4) ^ (lane & 7)) & 7) * 16;

  auto STAGE = [&](int t, int b) {   // 6 DMAs: 4 A + 2 B
    int ks = (t & 15) * 64;
    int cN = jlo + (t >> 4); if (cN >= NCP) cN -= NCP;
    const unsigned short* ws = wsrc + (size_t)cN * O_SZ * I_SZ + ks;
    unsigned short* Ad = &Abuf[b][(wid * 8) * BK];
    unsigned short* Bd = &Bbuf[b][(wid * 8) * BK];
    gload_lds16(xsP0 + ks, Ad);
    gload_lds16(xsP1 + ks, Ad + 64 * BK);
    gload_lds16(xsP2 + ks, Ad + 128 * BK);
    gload_lds16(xsP3 + ks, Ad + 192 * BK);
    gload_lds16(ws, Bd);
    gload_lds16(ws + (size_t)64 * I_SZ, Bd + 64 * BK);
  };

  // prologue: tiles 0,1 in flight (12 DMAs); tile 0 resident; c4 published
  STAGE(0, 0);
  STAGE(1, 1);
  asm volatile("s_waitcnt vmcnt(6)" ::: "memory");
  __builtin_amdgcn_sched_barrier(0);
  __syncthreads();

  int cur = 0;
  for (int t = 0; t < NTb; ++t) {
    const char* Ab = (const char*)&Abuf[cur][0];
    const char* Bb = (const char*)&Bbuf[cur][0];
    int st = cur + 2; if (st >= NBUF) st -= NBUF;

    // ---- kk=0 fragment reads ----
    bf16x8 af0[4], bf0[4], af1[4], bf1[4];
#pragma unroll
    for (int m = 0; m < 4; ++m)
      af0[m] = *reinterpret_cast<const bf16x8*>(
          Ab + (wr * 64 + m * 16) * 128 + lbase);
#pragma unroll
    for (int n = 0; n < 4; ++n)
      bf0[n] = *reinterpret_cast<const bf16x8*>(
          Bb + (wc * 64 + n * 16) * 128 + lbase);
    // ---- stage t+2 (vmcnt ops; do not disturb lgkm) ----
    if (t + 2 < NTb) STAGE(t + 2, st);
    asm volatile("s_waitcnt lgkmcnt(0)" ::: "memory");
    __builtin_amdgcn_sched_barrier(0);

    // ---- issue kk=1 reads: they fly under MFMA0 ----
#pragma unroll
    for (int m = 0; m < 4; ++m)
      af1[m] = *reinterpret_cast<const bf16x8*>(
          Ab + (wr * 64 + m * 16) * 128 + (lbase ^ 64));
#pragma unroll
    for (int n = 0; n < 4; ++n)
      bf1[n] = *reinterpret_cast<const bf16x8*>(
          Bb + (wc * 64 + n * 16) * 128 + (lbase ^ 64));
    __builtin_amdgcn_sched_barrier(0);  // pin kk1 issue before MFMA0

    __builtin_amdgcn_s_setprio(1);
#pragma unroll
    for (int m = 0; m < 4; ++m)
#pragma unroll
      for (int n = 0; n < 4; ++n)
        part[m][n] = __builtin_amdgcn_mfma_f32_16x16x32_bf16(
            af0[m], bf0[n], part[m][n], 0, 0, 0);
    __builtin_amdgcn_s_setprio(0);

    asm volatile("s_waitcnt lgkmcnt(0)" ::: "memory");  // kk1 frags landed
    __builtin_amdgcn_sched_barrier(0);

    __builtin_amdgcn_s_setprio(1);
#pragma unroll
    for (int m = 0; m < 4; ++m)
#pragma unroll
      for (int n = 0; n < 4; ++n)
        part[m][n] = __builtin_amdgcn_mfma_f32_16x16x32_bf16(
            af1[m], bf1[n], part[m][n], 0, 0, 0);
    __builtin_amdgcn_s_setprio(0);

    if ((t & 15) == 15) {  // chunk boundary: acc += c[row,chunk] * part
      int cj = jlo + (t >> 4); if (cj >= NCP) cj -= NCP;
#pragma unroll
      for (int m = 0; m < 4; ++m) {
        f32x4 cv = *reinterpret_cast<const f32x4*>(
            &c4[cj][wr * 64 + m * 16 + (lane >> 4) * 4]);
#pragma unroll
        for (int n = 0; n < 4; ++n) {
          acc[m][n] += cv * part[m][n];
          part[m][n] = (f32x4){0.f, 0.f, 0.f, 0.f};
        }
      }
    }

    // ---- tile boundary: counted vmcnt + SINGLE barrier ----
    if (t + 2 < NTb)
      asm volatile("s_waitcnt vmcnt(6)" ::: "memory");   // t+1 resident
    else
      asm volatile("s_waitcnt vmcnt(0)" ::: "memory");
    __builtin_amdgcn_sched_barrier(0);
    __builtin_amdgcn_s_barrier();
    ++cur; if (cur == NBUF) cur = 0;
  }

  // ---- epilogue: bias mix + scattered row store (f32) ----
#pragma unroll
  for (int n = 0; n < 4; ++n) {
    int col = bcol + wc * 64 + n * 16 + (lane & 15);
    float b6[NCP];
#pragma unroll
    for (int j = 0; j < NCP; ++j) b6[j] = bias[j * O_SZ + col];
#pragma unroll
    for (int m = 0; m < 4; ++m) {
#pragma unroll
      for (int r = 0; r < 4; ++r) {
        int rloc = wr * 64 + m * 16 + (lane >> 4) * 4 + r;
        float s = 0.f;
#pragma unroll
        for (int j = 0; j < NCP; ++j) s += c4[j][rloc] * b6[j];
        out[(size_t)pblk[rloc] * O_SZ + col] = acc[m][n][r] + s;
      }
    }
  }
}

extern "C" void kernel_launch(void* const* d_in, const int* in_sizes, int n_in,
                              void* d_out, int out_size, void* d_ws, size_t ws_size,
                              hipStream_t stream) {
  (void)in_sizes; (void)n_in; (void)out_size; (void)ws_size;
  const float* x     = (const float*)d_in[0];  // [B, I]
  const float* phase = (const float*)d_in[1];  // [B]
  const float* w     = (const float*)d_in[2];  // [C, O, I]
  const float* bias  = (const float*)d_in[3];  // [C, O]
  float* out = (float*)d_out;                  // [B, O] f32

  char* ws = (char*)d_ws;
  unsigned short* xb = (unsigned short*)ws;                          // 16 MB
  unsigned short* wb = (unsigned short*)(ws + (size_t)16 * 1024 * 1024);  // 12 MB
  unsigned short* perm = (unsigned short*)(ws + (size_t)28 * 1024 * 1024);  // 16 KB
  int* blkinfo = (int*)(ws + (size_t)28 * 1024 * 1024 + 16384);      // 256 B

  // fused prep: 1024 x-cast blocks + 1024 W-cast blocks + 1 sort block
  prep_all<<<2049, 1024, 0, stream>>>(x, xb, w, wb, phase, perm, blkinfo);

  dim3 grid((B_SZ / BM) * (O_SZ / BN));  // 32*8 = 256
  pfl_gemm<<<grid, 512, 0, stream>>>(xb, wb, phase, perm, blkinfo, bias, out);
}

// Round 22
// 103.698 us; speedup vs baseline: 2.4260x; 1.0681x over previous
//
#include <hip/hip_runtime.h>
#include <hip/hip_bf16.h>
#include <math.h>

#define B_SZ 8192
#define I_SZ 1024
#define O_SZ 1024
#define NCP  6

typedef __attribute__((ext_vector_type(8))) short bf16x8;
typedef __attribute__((ext_vector_type(4))) float f32x4;

__device__ __forceinline__ unsigned short f2bf(float f) {
  union { float f; unsigned int u; } v; v.f = f;
  unsigned int u = v.u;
  u += 0x7FFFu + ((u >> 16) & 1u);   // round-to-nearest-even
  return (unsigned short)(u >> 16);
}

__device__ __forceinline__ int seg_of(float ph) {
  const float two_pi = 6.2831855f;
  const float scale = (float)(6.0 / 6.283185307179586);
  float pm = fmodf(ph, two_pi);
  int bi = (int)floorf(pm * scale);
  return ((bi % NCP) + NCP) % NCP;   // identical mod logic to the GEMM's cc[]
}

// SINGLE fused prep kernel (verified R21):
//   blocks 0..1023    : cast x f32->bf16 (original row order)
//   blocks 1024..2047 : cast W f32->bf16
//   block  2048       : deterministic counting-sort of rows by segment
__global__ __launch_bounds__(1024) void prep_all(
    const float* __restrict__ x, unsigned short* __restrict__ xb,
    const float* __restrict__ w, unsigned short* __restrict__ wb,
    const float* __restrict__ phase,
    unsigned short* __restrict__ perm,
    int* __restrict__ blkinfo) {
  __shared__ int scanbuf[1024][NCP];  // 24 KB (sort block only)
  __shared__ int ownh[1024][NCP];     // 24 KB
  __shared__ int cum[NCP + 1];
  int t = (int)threadIdx.x;
  int b = (int)blockIdx.x;

  if (b < 1024) {            // ---- x cast ----
    const int n4 = B_SZ * I_SZ / 4;
    int idx = b * 1024 + t;
    for (int i = idx; i < n4; i += 1024 * 1024) {
      float4 v = reinterpret_cast<const float4*>(x)[i];
      ushort4 o;
      o.x = f2bf(v.x); o.y = f2bf(v.y); o.z = f2bf(v.z); o.w = f2bf(v.w);
      reinterpret_cast<ushort4*>(xb)[i] = o;
    }
    return;
  }
  if (b < 2048) {            // ---- W cast ----
    const int n4 = NCP * O_SZ * I_SZ / 4;
    int idx = (b - 1024) * 1024 + t;
    for (int i = idx; i < n4; i += 1024 * 1024) {
      float4 v = reinterpret_cast<const float4*>(w)[i];
      ushort4 o;
      o.x = f2bf(v.x); o.y = f2bf(v.y); o.z = f2bf(v.z); o.w = f2bf(v.w);
      reinterpret_cast<ushort4*>(wb)[i] = o;
    }
    return;
  }

  // ---- sort block ----
  int segs[8];
#pragma unroll
  for (int s = 0; s < NCP; ++s) scanbuf[t][s] = 0;
#pragma unroll
  for (int i = 0; i < 8; ++i) {
    segs[i] = seg_of(phase[t * 8 + i]);
    scanbuf[t][segs[i]]++;
  }
#pragma unroll
  for (int s = 0; s < NCP; ++s) ownh[t][s] = scanbuf[t][s];
  __syncthreads();
  for (int d = 1; d < 1024; d <<= 1) {   // Kogge-Stone inclusive scan
    int add[NCP];
    if (t >= d) {
#pragma unroll
      for (int s = 0; s < NCP; ++s) add[s] = scanbuf[t - d][s];
    }
    __syncthreads();
    if (t >= d) {
#pragma unroll
      for (int s = 0; s < NCP; ++s) scanbuf[t][s] += add[s];
    }
    __syncthreads();
  }
  if (t == 0) {
    cum[0] = 0;
    for (int s = 0; s < NCP; ++s) cum[s + 1] = cum[s] + scanbuf[1023][s];
  }
  __syncthreads();
#pragma unroll
  for (int s = 0; s < NCP; ++s)
    ownh[t][s] = cum[s] + scanbuf[t][s] - ownh[t][s];
#pragma unroll
  for (int i = 0; i < 8; ++i) {   // stable scatter (original row order)
    int s = segs[i];
    perm[ownh[t][s]++] = (unsigned short)(t * 8 + i);
  }
  if (t < B_SZ / 256) {   // 32 row-blocks of the sorted array
    int start = t * 256, end = start + 255;
    int s0 = 0; while (s0 < NCP - 1 && cum[s0 + 1] <= start) ++s0;
    int s1 = 0; while (s1 < NCP - 1 && cum[s1 + 1] <= end) ++s1;
    int nj = s1 - s0 + 4; if (nj > NCP) nj = NCP;
    blkinfo[2 * t] = (s0 + NCP - 1) % NCP;   // jlo
    blkinfo[2 * t + 1] = nj;
  }
}

__device__ __forceinline__ void gload_lds16(const void* g, void* l) {
  __builtin_amdgcn_global_load_lds(
      (const __attribute__((address_space(1))) void*)g,
      (__attribute__((address_space(3))) void*)l, 16, 0, 0);
}

#define BM 256
#define BN 128
#define BK 64
#define NBUF 3

// R21's verified GEMM with a CROSS-TILE fragment software-pipeline:
// two fragment register sets (A=kk0, B=kk1). Per tile:
//   read kk1(t) | STAGE(t+2) | lgkmcnt(8) [kk0(t) landed, kk1 flying]
//   MFMA0 | lgkmcnt(0) | vmcnt(6) | s_barrier
//   read kk0(t+1) from published next buffer | MFMA1 | fold?
// Every ds_read batch lands under an MFMA phase; the tile-top
// read-then-wait stall of the previous structure is gone. Barrier
// discipline identical (1/tile, always preceded by lgkm(0)+vmcnt):
// slot (t+1)%3's next writer is STAGE(t+4), two barriers after our read.
__global__ __launch_bounds__(512, 1) void pfl_gemm(
    const unsigned short* __restrict__ xb,   // ORIGINAL row order
    const unsigned short* __restrict__ wb,
    const float* __restrict__ phase,
    const unsigned short* __restrict__ perm,
    const int* __restrict__ blkinfo,
    const float* __restrict__ bias,
    float* __restrict__ out) {
  __shared__ __align__(16) unsigned short Abuf[NBUF][BM * BK];  // 3x32 KB
  __shared__ __align__(16) unsigned short Bbuf[NBUF][BN * BK];  // 3x16 KB
  __shared__ __align__(16) float c4[NCP][BM];                   // 6 KB
  __shared__ int pblk[BM];                                      // 1 KB

  const int nbn = O_SZ / BN;  // 8
  int bid = (int)blockIdx.x;  // 256 blocks (divisible by 8)
  int swz = (bid & 7) * 32 + (bid >> 3);  // bijective XCD remap
  int rowblk = swz / nbn;
  int brow = rowblk * BM;
  int bcol = (swz % nbn) * BN;

  int tid = (int)threadIdx.x;
  int lane = tid & 63;
  int wid = tid >> 6;        // 0..7
  int wr = wid >> 1;         // 0..3 (M)
  int wc = wid & 1;          // 0..1 (N)

  int jlo = blkinfo[2 * rowblk];
  int NTb = blkinfo[2 * rowblk + 1] << 4;   // NJ*16 tiles

  // ---- Catmull-Rom coefficients (via perm gather) + pblk ----
  if (tid < BM) {
    int orow = (int)perm[brow + tid];
    pblk[tid] = orow;
    float ph = phase[orow];
    const float two_pi = 6.2831855f;
    float pm = fmodf(ph, two_pi);
    float pos = pm * (float)(6.0 / 6.283185307179586);
    float base = floorf(pos);
    int bi = (int)base;
    float t = pos - base;
    float t2 = t * t, t3 = t2 * t;
    float w0 = -0.5f * t + t2 - 0.5f * t3;
    float w1 = 1.0f - 2.5f * t2 + 1.5f * t3;
    float w2 = 0.5f * t + 2.0f * t2 - 1.5f * t3;
    float w3 = -0.5f * t2 + 0.5f * t3;
    float cc[NCP] = {0.f, 0.f, 0.f, 0.f, 0.f, 0.f};
    cc[((bi - 1) % NCP + NCP) % NCP] += w0;
    cc[(bi % NCP + NCP) % NCP]       += w1;
    cc[((bi + 1) % NCP + NCP) % NCP] += w2;
    cc[((bi + 2) % NCP + NCP) % NCP] += w3;
    for (int j = 0; j < NCP; ++j) c4[j][tid] = cc[j];
  }

  f32x4 acc[4][4];   // folded result (VALU-touched once per 16 tiles)
  f32x4 part[4][4];  // pure MFMA chain within a chunk (AGPR-resident)
#pragma unroll
  for (int m = 0; m < 4; ++m)
#pragma unroll
    for (int n = 0; n < 4; ++n) {
      acc[m][n] = (f32x4){0.f, 0.f, 0.f, 0.f};
      part[m][n] = (f32x4){0.f, 0.f, 0.f, 0.f};
    }

  // staging: lane l -> LDS row (8-group + l>>3), linear 16B slot (l&7);
  // global source column pre-swizzled (slot xor row&7), rule #21.
  int swzcol = ((lane & 7) ^ (lane >> 3)) * 8;
  // A: per-lane PERMUTED row bases, one per 64-row group (computed once).
  int r0 = brow + wid * 8 + (lane >> 3);
  const unsigned short* xsP0 = xb + (size_t)perm[r0      ] * I_SZ + swzcol;
  const unsigned short* xsP1 = xb + (size_t)perm[r0 +  64] * I_SZ + swzcol;
  const unsigned short* xsP2 = xb + (size_t)perm[r0 + 128] * I_SZ + swzcol;
  const unsigned short* xsP3 = xb + (size_t)perm[r0 + 192] * I_SZ + swzcol;
  const unsigned short* wsrc =
      wb + (size_t)(bcol + wid * 8 + (lane >> 3)) * I_SZ + swzcol;

  // read-side swizzled base: slot = chunk ^ (row&7); row&7 == lane&7 here
  int lbase = (lane & 15) * 128 + (((lane >> 4) ^ (lane & 7)) & 7) * 16;

  auto STAGE = [&](int t, int b) {   // 6 DMAs: 4 A + 2 B
    int ks = (t & 15) * 64;
    int cN = jlo + (t >> 4); if (cN >= NCP) cN -= NCP;
    const unsigned short* ws = wsrc + (size_t)cN * O_SZ * I_SZ + ks;
    unsigned short* Ad = &Abuf[b][(wid * 8) * BK];
    unsigned short* Bd = &Bbuf[b][(wid * 8) * BK];
    gload_lds16(xsP0 + ks, Ad);
    gload_lds16(xsP1 + ks, Ad + 64 * BK);
    gload_lds16(xsP2 + ks, Ad + 128 * BK);
    gload_lds16(xsP3 + ks, Ad + 192 * BK);
    gload_lds16(ws, Bd);
    gload_lds16(ws + (size_t)64 * I_SZ, Bd + 64 * BK);
  };

  // prologue: tiles 0,1 in flight; tile 0 resident; c4 published
  STAGE(0, 0);
  STAGE(1, 1);
  asm volatile("s_waitcnt vmcnt(6)" ::: "memory");
  __builtin_amdgcn_sched_barrier(0);
  __syncthreads();

  bf16x8 afA[4], bfA[4], afB[4], bfB[4];
  {  // kk0(0) into regA
    const char* Ab = (const char*)&Abuf[0][0];
    const char* Bb = (const char*)&Bbuf[0][0];
#pragma unroll
    for (int m = 0; m < 4; ++m)
      afA[m] = *reinterpret_cast<const bf16x8*>(
          Ab + (wr * 64 + m * 16) * 128 + lbase);
#pragma unroll
    for (int n = 0; n < 4; ++n)
      bfA[n] = *reinterpret_cast<const bf16x8*>(
          Bb + (wc * 64 + n * 16) * 128 + lbase);
  }

  int cur = 0;
  for (int t = 0; t < NTb; ++t) {
    const char* Ab = (const char*)&Abuf[cur][0];
    const char* Bb = (const char*)&Bbuf[cur][0];
    int st = cur + 2; if (st >= NBUF) st -= NBUF;
    int nxt = cur + 1; if (nxt >= NBUF) nxt -= NBUF;

    // ---- kk1(t) reads -> regB (fly under MFMA0) ----
#pragma unroll
    for (int m = 0; m < 4; ++m)
      afB[m] = *reinterpret_cast<const bf16x8*>(
          Ab + (wr * 64 + m * 16) * 128 + (lbase ^ 64));
#pragma unroll
    for (int n = 0; n < 4; ++n)
      bfB[n] = *reinterpret_cast<const bf16x8*>(
          Bb + (wc * 64 + n * 16) * 128 + (lbase ^ 64));
    if (t + 2 < NTb) STAGE(t + 2, st);
    // regA (8 oldest LDS ops) landed; regB stays in flight
    asm volatile("s_waitcnt lgkmcnt(8)" ::: "memory");
    __builtin_amdgcn_sched_barrier(0);

    __builtin_amdgcn_s_setprio(1);
#pragma unroll
    for (int m = 0; m < 4; ++m)
#pragma unroll
      for (int n = 0; n < 4; ++n)
        part[m][n] = __builtin_amdgcn_mfma_f32_16x16x32_bf16(
            afA[m], bfA[n], part[m][n], 0, 0, 0);
    __builtin_amdgcn_s_setprio(0);

    asm volatile("s_waitcnt lgkmcnt(0)" ::: "memory");  // regB landed
    __builtin_amdgcn_sched_barrier(0);
    if (t + 2 < NTb)
      asm volatile("s_waitcnt vmcnt(6)" ::: "memory");   // t+1 resident
    else
      asm volatile("s_waitcnt vmcnt(0)" ::: "memory");
    __builtin_amdgcn_sched_barrier(0);
    __builtin_amdgcn_s_barrier();   // publishes buf[nxt] block-wide

    // ---- kk0(t+1) reads -> regA (land under MFMA1) ----
    if (t + 1 < NTb) {
      const char* Ab2 = (const char*)&Abuf[nxt][0];
      const char* Bb2 = (const char*)&Bbuf[nxt][0];
#pragma unroll
      for (int m = 0; m < 4; ++m)
        afA[m] = *reinterpret_cast<const bf16x8*>(
            Ab2 + (wr * 64 + m * 16) * 128 + lbase);
#pragma unroll
      for (int n = 0; n < 4; ++n)
        bfA[n] = *reinterpret_cast<const bf16x8*>(
            Bb2 + (wc * 64 + n * 16) * 128 + lbase);
    }
    __builtin_amdgcn_sched_barrier(0);  // pin reads before MFMA1

    __builtin_amdgcn_s_setprio(1);
#pragma unroll
    for (int m = 0; m < 4; ++m)
#pragma unroll
      for (int n = 0; n < 4; ++n)
        part[m][n] = __builtin_amdgcn_mfma_f32_16x16x32_bf16(
            afB[m], bfB[n], part[m][n], 0, 0, 0);
    __builtin_amdgcn_s_setprio(0);

    if ((t & 15) == 15) {  // chunk boundary: acc += c[row,chunk] * part
      int cj = jlo + (t >> 4); if (cj >= NCP) cj -= NCP;
#pragma unroll
      for (int m = 0; m < 4; ++m) {
        f32x4 cv = *reinterpret_cast<const f32x4*>(
            &c4[cj][wr * 64 + m * 16 + (lane >> 4) * 4]);
#pragma unroll
        for (int n = 0; n < 4; ++n) {
          acc[m][n] += cv * part[m][n];
          part[m][n] = (f32x4){0.f, 0.f, 0.f, 0.f};
        }
      }
    }
    cur = nxt;
  }

  // ---- epilogue: bias mix + scattered row store (f32) ----
#pragma unroll
  for (int n = 0; n < 4; ++n) {
    int col = bcol + wc * 64 + n * 16 + (lane & 15);
    float b6[NCP];
#pragma unroll
    for (int j = 0; j < NCP; ++j) b6[j] = bias[j * O_SZ + col];
#pragma unroll
    for (int m = 0; m < 4; ++m) {
#pragma unroll
      for (int r = 0; r < 4; ++r) {
        int rloc = wr * 64 + m * 16 + (lane >> 4) * 4 + r;
        float s = 0.f;
#pragma unroll
        for (int j = 0; j < NCP; ++j) s += c4[j][rloc] * b6[j];
        out[(size_t)pblk[rloc] * O_SZ + col] = acc[m][n][r] + s;
      }
    }
  }
}

extern "C" void kernel_launch(void* const* d_in, const int* in_sizes, int n_in,
                              void* d_out, int out_size, void* d_ws, size_t ws_size,
                              hipStream_t stream) {
  (void)in_sizes; (void)n_in; (void)out_size; (void)ws_size;
  const float* x     = (const float*)d_in[0];  // [B, I]
  const float* phase = (const float*)d_in[1];  // [B]
  const float* w     = (const float*)d_in[2];  // [C, O, I]
  const float* bias  = (const float*)d_in[3];  // [C, O]
  float* out = (float*)d_out;                  // [B, O] f32

  char* ws = (char*)d_ws;
  unsigned short* xb = (unsigned short*)ws;                          // 16 MB
  unsigned short* wb = (unsigned short*)(ws + (size_t)16 * 1024 * 1024);  // 12 MB
  unsigned short* perm = (unsigned short*)(ws + (size_t)28 * 1024 * 1024);  // 16 KB
  int* blkinfo = (int*)(ws + (size_t)28 * 1024 * 1024 + 16384);      // 256 B

  // fused prep: 1024 x-cast blocks + 1024 W-cast blocks + 1 sort block
  prep_all<<<2049, 1024, 0, stream>>>(x, xb, w, wb, phase, perm, blkinfo);

  dim3 grid((B_SZ / BM) * (O_SZ / BN));  // 32*8 = 256
  pfl_gemm<<<grid, 512, 0, stream>>>(xb, wb, phase, perm, blkinfo, bias, out);
}